// Round 1
// 611.961 us; speedup vs baseline: 1.1373x; 1.1373x over previous
//
#include <hip/hip_runtime.h>
#include <hip/hip_bf16.h>

#define N_NODES 200000
#define N_EDGES 1200000
#define IN_DIM  128
#define HID     64
#define NGRAPH  1024
#define NCLS    6
#define BN_EPS  1e-5f

#define TILE_N   64
#define ZS       68          // Ztmp row stride (floats); 272B = 17 banks shift, 2-way max
#define ECAP     1024

#define SCAN_CHUNK 1024
#define NBLK_SCAN ((N_NODES + SCAN_CHUNK - 1) / SCAN_CHUNK)   // 196

typedef short bf16x8 __attribute__((ext_vector_type(8)));
typedef float f32x4  __attribute__((ext_vector_type(4)));
#define MFMA16(a,b,c) __builtin_amdgcn_mfma_f32_16x16x32_bf16((a),(b),(c),0,0,0)

__device__ __forceinline__ unsigned short f2bf(float f) {
    union { __hip_bfloat16 h; unsigned short u; } v; v.h = __float2bfloat16(f); return v.u;
}
__device__ __forceinline__ float bfbits2f(unsigned short u) {
    union { unsigned int i; float f; } v; v.i = ((unsigned int)u) << 16; return v.f;
}
// float4 -> (hi bf16x4, lo bf16x4) packed as uint2 each
__device__ __forceinline__ void cvt4(const float4& x, uint2& hi, uint2& lo) {
    const unsigned short h0 = f2bf(x.x), h1 = f2bf(x.y), h2 = f2bf(x.z), h3 = f2bf(x.w);
    hi.x = (unsigned)h0 | ((unsigned)h1 << 16);
    hi.y = (unsigned)h2 | ((unsigned)h3 << 16);
    const unsigned short l0 = f2bf(x.x - bfbits2f(h0)), l1 = f2bf(x.y - bfbits2f(h1));
    const unsigned short l2 = f2bf(x.z - bfbits2f(h2)), l3 = f2bf(x.w - bfbits2f(h3));
    lo.x = (unsigned)l0 | ((unsigned)l1 << 16);
    lo.y = (unsigned)l2 | ((unsigned)l3 << 16);
}

// ===========================================================================
// Weight prep: pack W into MFMA B-fragment order (bf16 hi/lo planes).
// B-frag: lane l holds B[k = (l>>4)*8+j][n = l&15], j=0..7 contiguous.
// ===========================================================================
__global__ __launch_bounds__(256) void prep_emb_kernel(
    const float* __restrict__ w, unsigned short* __restrict__ wpe)   // [128][64] -> 16384
{
    const int idx = blockIdx.x * 256 + threadIdx.x;      // [ct2][s2][p1][l6][j3]
    if (idx >= 16384) return;
    const int j = idx & 7, l = (idx >> 3) & 63;
    const int plane = (idx >> 9) & 1, s = (idx >> 10) & 3, ct = (idx >> 12) & 3;
    const int n = ct * 16 + (l & 15);
    const int k = s * 32 + (l >> 4) * 8 + j;
    const float f = w[k * 64 + n];
    const unsigned short hb = f2bf(f);
    wpe[idx] = plane ? f2bf(f - bfbits2f(hb)) : hb;
}

__global__ __launch_bounds__(256) void prep_fc_kernel(
    const float* __restrict__ fc1, const float* __restrict__ fc2,
    unsigned short* __restrict__ wpf)                    // 3*2*8192 = 49152
{
    const int idx = blockIdx.x * 256 + threadIdx.x;      // [layer][g][ct2][s1][p1][l6][j3]
    if (idx >= 49152) return;
    const int j = idx & 7, l = (idx >> 3) & 63;
    const int plane = (idx >> 9) & 1, s = (idx >> 10) & 1, ct = (idx >> 11) & 3;
    const int g = (idx >> 13) & 1, layer = idx >> 14;
    const int n = ct * 16 + (l & 15);
    const int k = s * 32 + (l >> 4) * 8 + j;
    const float* W = g ? fc2 : fc1;
    const float f = W[(layer * 64 + k) * 64 + n];
    const unsigned short hb = f2bf(f);
    wpf[idx] = plane ? f2bf(f - bfbits2f(hb)) : hb;
}

// ===========================================================================
// CSR build (unchanged)
// ===========================================================================
__global__ __launch_bounds__(256) void hist_kernel(
    const int* __restrict__ dst, int* __restrict__ deg)
{
    const int e = blockIdx.x * 256 + threadIdx.x;
    if (e < N_EDGES) atomicAdd(&deg[dst[e]], 1);
}

__global__ __launch_bounds__(256) void scan_sum_kernel(
    const int* __restrict__ deg, int* __restrict__ bsum)
{
    __shared__ int sd[256];
    const int b = blockIdx.x, t = threadIdx.x;
    const int base = b * SCAN_CHUNK;
    int s = 0;
    #pragma unroll
    for (int i = 0; i < SCAN_CHUNK / 256; i++) {
        const int idx = base + t + i * 256;
        s += (idx < N_NODES) ? deg[idx] : 0;
    }
    sd[t] = s; __syncthreads();
    for (int off = 128; off > 0; off >>= 1) {
        if (t < off) sd[t] += sd[t + off];
        __syncthreads();
    }
    if (t == 0) bsum[b] = sd[0];
}

__global__ __launch_bounds__(256) void scan_block_kernel(
    const int* __restrict__ bsum, int* __restrict__ boff, int* __restrict__ offs)
{
    __shared__ int sd[256];
    const int t = threadIdx.x;
    const int v = (t < NBLK_SCAN) ? bsum[t] : 0;
    sd[t] = v; __syncthreads();
    for (int off = 1; off < 256; off <<= 1) {
        const int u = (t >= off) ? sd[t - off] : 0;
        __syncthreads();
        sd[t] += u;
        __syncthreads();
    }
    if (t < NBLK_SCAN) boff[t] = sd[t] - v;
    if (t == 0) offs[N_NODES] = N_EDGES;
}

__global__ __launch_bounds__(256) void scan_scatter_kernel(
    const int* __restrict__ deg, const int* __restrict__ boff, int* __restrict__ offs)
{
    __shared__ int sd[256];
    const int b = blockIdx.x, t = threadIdx.x;
    const int base = b * SCAN_CHUNK + t * 4;
    int d0 = 0, d1 = 0, d2 = 0, d3 = 0;
    if (base + 0 < N_NODES) d0 = deg[base + 0];
    if (base + 1 < N_NODES) d1 = deg[base + 1];
    if (base + 2 < N_NODES) d2 = deg[base + 2];
    if (base + 3 < N_NODES) d3 = deg[base + 3];
    const int ts = d0 + d1 + d2 + d3;
    sd[t] = ts; __syncthreads();
    for (int off = 1; off < 256; off <<= 1) {
        const int u = (t >= off) ? sd[t - off] : 0;
        __syncthreads();
        sd[t] += u;
        __syncthreads();
    }
    const int excl = sd[t] - ts + boff[b];
    if (base + 0 < N_NODES) offs[base + 0] = excl;
    if (base + 1 < N_NODES) offs[base + 1] = excl + d0;
    if (base + 2 < N_NODES) offs[base + 2] = excl + d0 + d1;
    if (base + 3 < N_NODES) offs[base + 3] = excl + d0 + d1 + d2;
}

__global__ __launch_bounds__(256) void bucket_kernel(
    const int* __restrict__ src, const int* __restrict__ dst,
    int* __restrict__ cursor, int* __restrict__ csr_src)
{
    const int e = blockIdx.x * 256 + threadIdx.x;
    if (e < N_EDGES) {
        const int pos = atomicAdd(&cursor[dst[e]], 1);
        csr_src[pos] = src[e];
    }
}

// ===========================================================================
// Graph segment offsets: batch is sorted, so goffs[g] = lower_bound(batch, g).
// 1025 threads, 18 L2-resident reads each — trivial cost, removes all pooling
// atomics and the per-node branch.
// ===========================================================================
__global__ __launch_bounds__(256) void graph_offs_kernel(
    const int* __restrict__ batch, int* __restrict__ goffs)
{
    const int g = blockIdx.x * 256 + threadIdx.x;
    if (g > NGRAPH) return;
    if (g == NGRAPH) { goffs[NGRAPH] = N_NODES; return; }
    int lo = 0, hi = N_NODES;
    while (lo < hi) {
        const int mid = (lo + hi) >> 1;
        if (batch[mid] < g) lo = mid + 1; else hi = mid;
    }
    goffs[g] = lo;
}

// ===========================================================================
// Pool: one 256-thread block per graph. 16 threads cover one node (float4),
// 16 nodes per block-iteration (1 KB coalesced). No atomics, no branches.
// 1024 blocks = 4 blocks/CU -> streaming-bound, not latency-bound.
// ===========================================================================
__global__ __launch_bounds__(256) void pool_kernel(
    const float* __restrict__ h, const int* __restrict__ goffs,
    float* __restrict__ pooled, float* __restrict__ cnt)
{
    __shared__ float4 red[4][16];
    const int g = blockIdx.x, t = threadIdx.x;
    const int s = goffs[g], e = goffs[g + 1];
    const int grp = t >> 4;      // node group 0..15
    const int q = t & 15;        // float4 slot within node
    float4 acc = {0.f, 0.f, 0.f, 0.f};
    for (int n = s + grp; n < e; n += 16) {
        const float4 v = *(const float4*)(h + (size_t)n * HID + q * 4);
        acc.x += v.x; acc.y += v.y; acc.z += v.z; acc.w += v.w;
    }
    // reduce across the 4 node-groups within each wave (lane bits 4,5)
    #pragma unroll
    for (int off = 16; off <= 32; off <<= 1) {
        acc.x += __shfl_xor(acc.x, off, 64);
        acc.y += __shfl_xor(acc.y, off, 64);
        acc.z += __shfl_xor(acc.z, off, 64);
        acc.w += __shfl_xor(acc.w, off, 64);
    }
    const int wv = t >> 6, lane = t & 63;
    if (lane < 16) red[wv][lane] = acc;
    __syncthreads();
    if (t < 16) {
        float4 a = red[0][t];
        const float4 b = red[1][t], c = red[2][t], d = red[3][t];
        a.x += b.x + c.x + d.x;
        a.y += b.y + c.y + d.y;
        a.z += b.z + c.z + d.z;
        a.w += b.w + c.w + d.w;
        *(float4*)(pooled + (size_t)g * HID + t * 4) = a;
    }
    if (t == 0) cnt[g] = (float)(e - s);
}

// ===========================================================================
// Embed: h0 = relu(bn(x @ W + b)) via split-bf16 MFMA.
// x tile converted on load into A-fragment-order LDS (lane-linear 16B slots).
// W prepacked B-frags loaded straight from global.
// ===========================================================================
__global__ __launch_bounds__(256) void embed_kernel(
    const float* __restrict__ x, const unsigned short* __restrict__ wpe,
    const float* __restrict__ bias,
    const float* __restrict__ bn_g, const float* __restrict__ bn_b,
    const float* __restrict__ bn_m, const float* __restrict__ bn_v,
    float* __restrict__ h)
{
    __shared__ __align__(16) short Abuf[4 * 4 * 2 * 64 * 8];   // 32 KB
    __shared__ float Ztmp[TILE_N * ZS];                        // 17408 B
    __shared__ float BNs[128];
    const int t = threadIdx.x, lane = t & 63, w = t >> 6;
    const int base = blockIdx.x * TILE_N;

    if (t < 64) {
        const float s = bn_g[t] * rsqrtf(bn_v[t] + BN_EPS);
        BNs[t] = s;
        BNs[64 + t] = bias[t] * s + bn_b[t] - bn_m[t] * s;
    }
    // stage + hi/lo convert x tile into A-frag order
    #pragma unroll
    for (int i = 0; i < 8; i++) {
        const int idx = t + i * 256;                 // 0..2047
        const int n = idx >> 5, k4 = idx & 31;
        const float4 v = *(const float4*)(x + (size_t)(base + n) * IN_DIM + k4 * 4);
        uint2 hi, lo; cvt4(v, hi, lo);
        const int s = k4 >> 3, lc = (n & 15) + 16 * ((k4 >> 1) & 3);
        const int half = k4 & 1, wm = n >> 4;
        *(uint2*)&Abuf[(((wm * 4 + s) * 2 + 0) * 64 + lc) * 8 + half * 4] = hi;
        *(uint2*)&Abuf[(((wm * 4 + s) * 2 + 1) * 64 + lc) * 8 + half * 4] = lo;
    }
    __syncthreads();

    const bf16x8* A = (const bf16x8*)Abuf;
    const bf16x8* B = (const bf16x8*)wpe;
    bf16x8 ah[4], al[4];
    #pragma unroll
    for (int s = 0; s < 4; s++) {
        ah[s] = A[((w * 4 + s) * 2 + 0) * 64 + lane];
        al[s] = A[((w * 4 + s) * 2 + 1) * 64 + lane];
    }
    const int q = lane >> 4, c = lane & 15;
    #pragma unroll
    for (int ct = 0; ct < 4; ct++) {
        f32x4 acc = {0.f, 0.f, 0.f, 0.f};
        #pragma unroll
        for (int s = 0; s < 4; s++) {
            const bf16x8 bh = B[(ct << 9) + (s << 7) + lane];
            const bf16x8 bl = B[(ct << 9) + (s << 7) + 64 + lane];
            acc = MFMA16(ah[s], bh, acc);
            acc = MFMA16(ah[s], bl, acc);
            acc = MFMA16(al[s], bh, acc);
        }
        const int n = ct * 16 + c;
        const float sc = BNs[n], sh = BNs[64 + n];
        #pragma unroll
        for (int r = 0; r < 4; r++)
            Ztmp[(w * 16 + q * 4 + r) * ZS + n] = fmaxf(acc[r] * sc + sh, 0.f);
    }
    __syncthreads();
    #pragma unroll
    for (int i = 0; i < 4; i++) {
        const int idx = t + i * 256, n = idx >> 4, k4 = idx & 15;
        *(float4*)(h + (size_t)(base + n) * HID + k4 * 4) =
            *(const float4*)(&Ztmp[n * ZS + k4 * 4]);
    }
}

// ===========================================================================
// Fused GIN layer: r7's gather (branch-free clamped 4-deep, LDS edge cache)
// -> split-bf16 MFMA GEMM1 -> bn/relu -> re-split -> MFMA GEMM2 -> bn/relu.
// Weights prepacked B-frags from global; A-frags in lane-linear LDS.
// ===========================================================================
__global__ __launch_bounds__(256) void agg_mlp_kernel(
    const float* __restrict__ hin, float* __restrict__ hout,
    const int* __restrict__ offs, const int* __restrict__ csr,
    const unsigned short* __restrict__ wp1, const unsigned short* __restrict__ wp2,
    const float* __restrict__ b1, const float* __restrict__ g1,
    const float* __restrict__ bb1, const float* __restrict__ m1, const float* __restrict__ v1,
    const float* __restrict__ b2, const float* __restrict__ g2,
    const float* __restrict__ bb2, const float* __restrict__ m2, const float* __restrict__ v2)
{
    __shared__ __align__(16) short Abuf[4 * 2 * 2 * 64 * 8];   // 16 KB
    __shared__ float Ztmp[TILE_N * ZS];                        // 17408 B
    __shared__ int   OF[TILE_N + 1];
    __shared__ int   EIDX[ECAP];                               // 4 KB
    __shared__ float BNs[256];
    const int t = threadIdx.x, lane = t & 63, w = t >> 6;
    const int sub = lane >> 4, cq = lane & 15;
    const int base = blockIdx.x * TILE_N;

    if (t < 64) {
        const float sa = g1[t] * rsqrtf(v1[t] + BN_EPS);
        BNs[t] = sa; BNs[64 + t] = b1[t] * sa + bb1[t] - m1[t] * sa;
        const float sb = g2[t] * rsqrtf(v2[t] + BN_EPS);
        BNs[128 + t] = sb; BNs[192 + t] = b2[t] * sb + bb2[t] - m2[t] * sb;
    }
    if (t <= TILE_N) OF[t] = offs[base + t];
    const int segStart = offs[base];
    const int segEnd   = offs[base + TILE_N];
    for (int i = t; i < segEnd - segStart; i += 256)
        if (i < ECAP) EIDX[i] = csr[segStart + i];
    __syncthreads();

    // gather -> A-frag hi/lo writes
    const float* __restrict__ hc = hin + cq * 4;
    #pragma unroll
    for (int p = 0; p < 4; p++) {
        const int mloc = p * 4 + sub, nl = w * 16 + mloc;
        const int e0 = OF[nl], e1 = OF[nl + 1];
        float4 acc = *(const float4*)(hin + (size_t)(base + nl) * HID + cq * 4);
        if (e0 < e1) {
            const int e1m = e1 - 1;
            for (int e = e0; e < e1; e += 4) {
                const int ea = e;
                const int eb = (e + 1 < e1) ? e + 1 : e1m;
                const int ec = (e + 2 < e1) ? e + 2 : e1m;
                const int ed = (e + 3 < e1) ? e + 3 : e1m;
                const int la = ea - segStart, lb = eb - segStart;
                const int lc2 = ec - segStart, ld = ed - segStart;
                const int s0 = (la < ECAP) ? EIDX[la] : csr[ea];
                const int s1 = (lb < ECAP) ? EIDX[lb] : csr[eb];
                const int s2 = (lc2 < ECAP) ? EIDX[lc2] : csr[ec];
                const int s3 = (ld < ECAP) ? EIDX[ld] : csr[ed];
                const float4 v0 = *(const float4*)(hc + (size_t)s0 * HID);
                const float4 v1_ = *(const float4*)(hc + (size_t)s1 * HID);
                const float4 v2_ = *(const float4*)(hc + (size_t)s2 * HID);
                const float4 v3_ = *(const float4*)(hc + (size_t)s3 * HID);
                const float mk1 = (e + 1 < e1) ? 1.f : 0.f;
                const float mk2 = (e + 2 < e1) ? 1.f : 0.f;
                const float mk3 = (e + 3 < e1) ? 1.f : 0.f;
                acc.x += v0.x + mk1 * v1_.x + mk2 * v2_.x + mk3 * v3_.x;
                acc.y += v0.y + mk1 * v1_.y + mk2 * v2_.y + mk3 * v3_.y;
                acc.z += v0.z + mk1 * v1_.z + mk2 * v2_.z + mk3 * v3_.z;
                acc.w += v0.w + mk1 * v1_.w + mk2 * v2_.w + mk3 * v3_.w;
            }
        }
        uint2 hi, lo; cvt4(acc, hi, lo);
        const int s = cq >> 3, lc = mloc + 16 * ((cq >> 1) & 3), half = cq & 1;
        *(uint2*)&Abuf[(((w * 2 + s) * 2 + 0) * 64 + lc) * 8 + half * 4] = hi;
        *(uint2*)&Abuf[(((w * 2 + s) * 2 + 1) * 64 + lc) * 8 + half * 4] = lo;
    }
    __syncthreads();

    const bf16x8* A = (const bf16x8*)Abuf;
    const int q = lane >> 4, c = lane & 15;

    // GEMM1
    {
        const bf16x8 a0h = A[((w * 2 + 0) * 2 + 0) * 64 + lane];
        const bf16x8 a0l = A[((w * 2 + 0) * 2 + 1) * 64 + lane];
        const bf16x8 a1h = A[((w * 2 + 1) * 2 + 0) * 64 + lane];
        const bf16x8 a1l = A[((w * 2 + 1) * 2 + 1) * 64 + lane];
        const bf16x8* B = (const bf16x8*)wp1;
        #pragma unroll
        for (int ct = 0; ct < 4; ct++) {
            const bf16x8 b0h = B[(ct << 8) + lane];
            const bf16x8 b0l = B[(ct << 8) + 64 + lane];
            const bf16x8 b1h_ = B[(ct << 8) + 128 + lane];
            const bf16x8 b1l_ = B[(ct << 8) + 192 + lane];
            f32x4 acc = {0.f, 0.f, 0.f, 0.f};
            acc = MFMA16(a0h, b0h, acc);
            acc = MFMA16(a0h, b0l, acc);
            acc = MFMA16(a0l, b0h, acc);
            acc = MFMA16(a1h, b1h_, acc);
            acc = MFMA16(a1h, b1l_, acc);
            acc = MFMA16(a1l, b1h_, acc);
            const int n = ct * 16 + c;
            const float sc = BNs[n], sh = BNs[64 + n];
            #pragma unroll
            for (int r = 0; r < 4; r++)
                Ztmp[(w * 16 + q * 4 + r) * ZS + n] = fmaxf(acc[r] * sc + sh, 0.f);
        }
    }
    __syncthreads();    // Ztmp complete; Abuf free

    // re-split t1 into A-frags
    {
        const int m = t >> 2;
        #pragma unroll
        for (int d = 0; d < 4; d++) {
            const int k4 = (t & 3) * 4 + d;
            const float4 v = *(const float4*)(&Ztmp[m * ZS + k4 * 4]);
            uint2 hi, lo; cvt4(v, hi, lo);
            const int s = k4 >> 3, lc = (m & 15) + 16 * ((k4 >> 1) & 3);
            const int half = k4 & 1, wm = m >> 4;
            *(uint2*)&Abuf[(((wm * 2 + s) * 2 + 0) * 64 + lc) * 8 + half * 4] = hi;
            *(uint2*)&Abuf[(((wm * 2 + s) * 2 + 1) * 64 + lc) * 8 + half * 4] = lo;
        }
    }
    __syncthreads();

    // GEMM2
    {
        const bf16x8 a0h = A[((w * 2 + 0) * 2 + 0) * 64 + lane];
        const bf16x8 a0l = A[((w * 2 + 0) * 2 + 1) * 64 + lane];
        const bf16x8 a1h = A[((w * 2 + 1) * 2 + 0) * 64 + lane];
        const bf16x8 a1l = A[((w * 2 + 1) * 2 + 1) * 64 + lane];
        const bf16x8* B = (const bf16x8*)wp2;
        #pragma unroll
        for (int ct = 0; ct < 4; ct++) {
            const bf16x8 b0h = B[(ct << 8) + lane];
            const bf16x8 b0l = B[(ct << 8) + 64 + lane];
            const bf16x8 b1h_ = B[(ct << 8) + 128 + lane];
            const bf16x8 b1l_ = B[(ct << 8) + 192 + lane];
            f32x4 acc = {0.f, 0.f, 0.f, 0.f};
            acc = MFMA16(a0h, b0h, acc);
            acc = MFMA16(a0h, b0l, acc);
            acc = MFMA16(a0l, b0h, acc);
            acc = MFMA16(a1h, b1h_, acc);
            acc = MFMA16(a1h, b1l_, acc);
            acc = MFMA16(a1l, b1h_, acc);
            const int n = ct * 16 + c;
            const float sc = BNs[128 + n], sh = BNs[192 + n];
            #pragma unroll
            for (int r = 0; r < 4; r++)
                Ztmp[(w * 16 + q * 4 + r) * ZS + n] = fmaxf(acc[r] * sc + sh, 0.f);
        }
    }
    __syncthreads();

    #pragma unroll
    for (int i = 0; i < 4; i++) {
        const int idx = t + i * 256, n = idx >> 4, k4 = idx & 15;
        *(float4*)(hout + (size_t)(base + n) * HID + k4 * 4) =
            *(const float4*)(&Ztmp[n * ZS + k4 * 4]);
    }
}

// ===========================================================================
// Classifier (unchanged)
// ===========================================================================
__global__ __launch_bounds__(64) void cls_kernel(
    const float* __restrict__ pooled, const float* __restrict__ cnt,
    const float* __restrict__ w1, const float* __restrict__ b1,
    const float* __restrict__ w2, const float* __restrict__ b2,
    float* __restrict__ out)
{
    const int g = blockIdx.x;
    const int lane = threadIdx.x;
    const float c = cnt[g];
    const float p = pooled[(size_t)g * HID + lane] / fmaxf(c, 1.f);
    float acc = (lane < 32) ? b1[lane] : 0.f;
    #pragma unroll
    for (int k = 0; k < 64; k++) {
        const float pk = __shfl(p, k, 64);
        if (lane < 32) acc += pk * w1[k * 32 + lane];
    }
    const float hmid = fmaxf(acc, 0.f);
    float acc2 = (lane < NCLS) ? b2[lane] : 0.f;
    #pragma unroll
    for (int k = 0; k < 32; k++) {
        const float hk = __shfl(hmid, k, 64);
        if (lane < NCLS) acc2 += hk * w2[k * NCLS + lane];
    }
    if (lane < NCLS) out[(size_t)g * NCLS + lane] = acc2;
}

// ===========================================================================
extern "C" void kernel_launch(void* const* d_in, const int* in_sizes, int n_in,
                              void* d_out, int out_size, void* d_ws, size_t ws_size,
                              hipStream_t stream) {
    const float* x     = (const float*)d_in[0];
    const int*   ei    = (const int*)d_in[1];
    const int*   batch = (const int*)d_in[2];
    const float* emb_w = (const float*)d_in[3];
    const float* emb_b = (const float*)d_in[4];
    const float* ibn_g = (const float*)d_in[5];
    const float* ibn_b = (const float*)d_in[6];
    const float* ibn_m = (const float*)d_in[7];
    const float* ibn_v = (const float*)d_in[8];
    const float* fc1_w = (const float*)d_in[9];
    const float* fc1_b = (const float*)d_in[10];
    const float* mbn_g = (const float*)d_in[11];
    const float* mbn_b = (const float*)d_in[12];
    const float* mbn_m = (const float*)d_in[13];
    const float* mbn_v = (const float*)d_in[14];
    const float* fc2_w = (const float*)d_in[15];
    const float* fc2_b = (const float*)d_in[16];
    const float* obn_g = (const float*)d_in[17];
    const float* obn_b = (const float*)d_in[18];
    const float* obn_m = (const float*)d_in[19];
    const float* obn_v = (const float*)d_in[20];
    const float* cls1w = (const float*)d_in[21];
    const float* cls1b = (const float*)d_in[22];
    const float* cls2w = (const float*)d_in[23];
    const float* cls2b = (const float*)d_in[24];

    float* h0     = (float*)d_ws;
    float* h1     = h0 + (size_t)N_NODES * HID;
    float* pooled = h1 + (size_t)N_NODES * HID;
    float* cnt    = pooled + NGRAPH * HID;
    int*   deg    = (int*)(cnt + NGRAPH);
    int*   offs   = deg + N_NODES;
    int*   bsum   = offs + (N_NODES + 1);
    int*   boff   = bsum + NBLK_SCAN;
    int*   csr    = boff + NBLK_SCAN;
    unsigned short* wpe = (unsigned short*)(csr + N_EDGES);   // 16384
    unsigned short* wpf = wpe + 16384;                        // 49152
    int*   goffs  = (int*)(wpf + 49152);                      // NGRAPH+1

    const int* src = ei;
    const int* dst = ei + N_EDGES;

    // weight prep (B-fragment packing, hi/lo planes)
    prep_emb_kernel<<<64, 256, 0, stream>>>(emb_w, wpe);
    prep_fc_kernel<<<192, 256, 0, stream>>>(fc1_w, fc2_w, wpf);

    // graph segment offsets (batch is sorted)
    graph_offs_kernel<<<(NGRAPH + 256) / 256, 256, 0, stream>>>(batch, goffs);

    // CSR build
    hipMemsetAsync(deg, 0, N_NODES * sizeof(int), stream);
    hist_kernel<<<(N_EDGES + 255) / 256, 256, 0, stream>>>(dst, deg);
    scan_sum_kernel<<<NBLK_SCAN, 256, 0, stream>>>(deg, bsum);
    scan_block_kernel<<<1, 256, 0, stream>>>(bsum, boff, offs);
    scan_scatter_kernel<<<NBLK_SCAN, 256, 0, stream>>>(deg, boff, offs);
    hipMemcpyAsync(deg, offs, N_NODES * sizeof(int), hipMemcpyDeviceToDevice, stream);
    bucket_kernel<<<(N_EDGES + 255) / 256, 256, 0, stream>>>(src, dst, deg, csr);

    // network
    const int gemm_blocks = N_NODES / TILE_N;   // 3125
    embed_kernel<<<gemm_blocks, 256, 0, stream>>>(x, wpe, emb_b,
                                                  ibn_g, ibn_b, ibn_m, ibn_v, h0);

    const float* hin = h0;
    float* hout = h1;
    for (int i = 0; i < 3; i++) {
        agg_mlp_kernel<<<gemm_blocks, 256, 0, stream>>>(
            hin, hout, offs, csr,
            wpf + (size_t)(i * 2 + 0) * 8192, wpf + (size_t)(i * 2 + 1) * 8192,
            fc1_b + i * HID, mbn_g + i * HID, mbn_b + i * HID, mbn_m + i * HID, mbn_v + i * HID,
            fc2_b + i * HID, obn_g + i * HID, obn_b + i * HID, obn_m + i * HID, obn_v + i * HID);
        const float* tmp = hin; hin = hout; hout = (float*)tmp;
    }

    // pool: one block per graph, no atomics
    pool_kernel<<<NGRAPH, 256, 0, stream>>>(h1, goffs, pooled, cnt);

    cls_kernel<<<NGRAPH, 64, 0, stream>>>(pooled, cnt, cls1w, cls1b, cls2w, cls2b,
                                          (float*)d_out);
}

// Round 2
// 526.876 us; speedup vs baseline: 1.3210x; 1.1615x over previous
//
#include <hip/hip_runtime.h>
#include <hip/hip_bf16.h>

#define N_NODES 200000
#define N_EDGES 1200000
#define IN_DIM  128
#define HID     64
#define NGRAPH  1024
#define NCLS    6
#define BN_EPS  1e-5f

#define TILE_N   64
#define ZS       68          // Ztmp row stride (floats); 272B = 17 banks shift, 2-way max
#define ECAP     1024

#define SCAN_CHUNK 1024
#define NBLK_SCAN ((N_NODES + SCAN_CHUNK - 1) / SCAN_CHUNK)   // 196

// ---- binned CSR build ----
#define NBKT   128           // dst-range buckets
#define BRANGE 1568          // nodes per bucket (128*1568 = 200704 >= N)
#define BCAP   12288         // per-bucket edge capacity (mean 9408, sigma ~97)
#define EPB    4096          // edges per bin_kernel block
#define NB_BIN ((N_EDGES + EPB - 1) / EPB)   // 293

typedef short bf16x8 __attribute__((ext_vector_type(8)));
typedef float f32x4  __attribute__((ext_vector_type(4)));
#define MFMA16(a,b,c) __builtin_amdgcn_mfma_f32_16x16x32_bf16((a),(b),(c),0,0,0)

__device__ __forceinline__ unsigned short f2bf(float f) {
    union { __hip_bfloat16 h; unsigned short u; } v; v.h = __float2bfloat16(f); return v.u;
}
__device__ __forceinline__ float bfbits2f(unsigned short u) {
    union { unsigned int i; float f; } v; v.i = ((unsigned int)u) << 16; return v.f;
}
// float4 -> (hi bf16x4, lo bf16x4) packed as uint2 each
__device__ __forceinline__ void cvt4(const float4& x, uint2& hi, uint2& lo) {
    const unsigned short h0 = f2bf(x.x), h1 = f2bf(x.y), h2 = f2bf(x.z), h3 = f2bf(x.w);
    hi.x = (unsigned)h0 | ((unsigned)h1 << 16);
    hi.y = (unsigned)h2 | ((unsigned)h3 << 16);
    const unsigned short l0 = f2bf(x.x - bfbits2f(h0)), l1 = f2bf(x.y - bfbits2f(h1));
    const unsigned short l2 = f2bf(x.z - bfbits2f(h2)), l3 = f2bf(x.w - bfbits2f(h3));
    lo.x = (unsigned)l0 | ((unsigned)l1 << 16);
    lo.y = (unsigned)l2 | ((unsigned)l3 << 16);
}

// ===========================================================================
// Weight prep: pack W into MFMA B-fragment order (bf16 hi/lo planes).
// ===========================================================================
__global__ __launch_bounds__(256) void prep_emb_kernel(
    const float* __restrict__ w, unsigned short* __restrict__ wpe)   // [128][64] -> 16384
{
    const int idx = blockIdx.x * 256 + threadIdx.x;      // [ct2][s2][p1][l6][j3]
    if (idx >= 16384) return;
    const int j = idx & 7, l = (idx >> 3) & 63;
    const int plane = (idx >> 9) & 1, s = (idx >> 10) & 3, ct = (idx >> 12) & 3;
    const int n = ct * 16 + (l & 15);
    const int k = s * 32 + (l >> 4) * 8 + j;
    const float f = w[k * 64 + n];
    const unsigned short hb = f2bf(f);
    wpe[idx] = plane ? f2bf(f - bfbits2f(hb)) : hb;
}

__global__ __launch_bounds__(256) void prep_fc_kernel(
    const float* __restrict__ fc1, const float* __restrict__ fc2,
    unsigned short* __restrict__ wpf)                    // 3*2*8192 = 49152
{
    const int idx = blockIdx.x * 256 + threadIdx.x;      // [layer][g][ct2][s1][p1][l6][j3]
    if (idx >= 49152) return;
    const int j = idx & 7, l = (idx >> 3) & 63;
    const int plane = (idx >> 9) & 1, s = (idx >> 10) & 1, ct = (idx >> 11) & 3;
    const int g = (idx >> 13) & 1, layer = idx >> 14;
    const int n = ct * 16 + (l & 15);
    const int k = s * 32 + (l >> 4) * 8 + j;
    const float* W = g ? fc2 : fc1;
    const float f = W[(layer * 64 + k) * 64 + n];
    const unsigned short hb = f2bf(f);
    wpf[idx] = plane ? f2bf(f - bfbits2f(hb)) : hb;
}

// ===========================================================================
// Binned CSR build.
// bin_kernel: partition edges into NBKT dst-range buckets; per-block LDS
// histogram -> one global atomicAdd per bucket -> contiguous (src,dst) writes.
// ===========================================================================
__global__ __launch_bounds__(256) void bin_kernel(
    const int* __restrict__ src, const int* __restrict__ dst,
    int* __restrict__ gcnt, uint2* __restrict__ ebin)
{
    __shared__ int hist[NBKT];
    __shared__ int basis[NBKT];
    const int t = threadIdx.x;
    const int base = blockIdx.x * EPB;
    if (t < NBKT) hist[t] = 0;
    __syncthreads();
    int sv[16], dv[16];
    #pragma unroll
    for (int i = 0; i < 16; i++) {
        const int e = base + t + i * 256;
        if (e < N_EDGES) {
            sv[i] = src[e]; dv[i] = dst[e];
            atomicAdd(&hist[dv[i] / BRANGE], 1);
        } else { sv[i] = -1; dv[i] = -1; }
    }
    __syncthreads();
    if (t < NBKT) { basis[t] = atomicAdd(&gcnt[t], hist[t]); hist[t] = 0; }
    __syncthreads();
    #pragma unroll
    for (int i = 0; i < 16; i++) {
        if (dv[i] >= 0) {
            const int bb = dv[i] / BRANGE;
            const int pos = basis[bb] + atomicAdd(&hist[bb], 1);
            ebin[(size_t)bb * BCAP + pos] = make_uint2((unsigned)sv[i], (unsigned)dv[i]);
        }
    }
}

// bindeg: per-bucket LDS histogram -> dense deg write (replaces hist_kernel
// and its 1.2M random global atomics; also covers the deg memset).
__global__ __launch_bounds__(512) void bindeg_kernel(
    const int* __restrict__ gcnt, const uint2* __restrict__ ebin,
    int* __restrict__ deg)
{
    __shared__ int hist[BRANGE];
    const int b = blockIdx.x, t = threadIdx.x;
    for (int i = t; i < BRANGE; i += 512) hist[i] = 0;
    __syncthreads();
    const int cnt = gcnt[b];
    const int r0 = b * BRANGE;
    const uint2* __restrict__ eb = ebin + (size_t)b * BCAP;
    for (int i = t; i < cnt; i += 512)
        atomicAdd(&hist[(int)eb[i].y - r0], 1);
    __syncthreads();
    for (int i = t; i < BRANGE; i += 512)
        if (r0 + i < N_NODES) deg[r0 + i] = hist[i];
}

// binscatter: one block owns one bucket's contiguous csr region (~75 KB);
// cursors in LDS; dirty L2 lines fill completely -> writeback = 4.8 MB total.
__global__ __launch_bounds__(512) void binscatter_kernel(
    const int* __restrict__ gcnt, const uint2* __restrict__ ebin,
    const int* __restrict__ offs, int* __restrict__ csr_src)
{
    __shared__ int cur[BRANGE];
    const int b = blockIdx.x, t = threadIdx.x;
    const int r0 = b * BRANGE;
    const int lim = (r0 + BRANGE <= N_NODES) ? BRANGE : (N_NODES - r0);
    for (int i = t; i < lim; i += 512) cur[i] = offs[r0 + i];
    __syncthreads();
    const int cnt = gcnt[b];
    const uint2* __restrict__ eb = ebin + (size_t)b * BCAP;
    for (int i = t; i < cnt; i += 512) {
        const uint2 e = eb[i];
        const int pos = atomicAdd(&cur[(int)e.y - r0], 1);
        csr_src[pos] = (int)e.x;
    }
}

// ===========================================================================
// Prefix scan over deg (unchanged)
// ===========================================================================
__global__ __launch_bounds__(256) void scan_sum_kernel(
    const int* __restrict__ deg, int* __restrict__ bsum)
{
    __shared__ int sd[256];
    const int b = blockIdx.x, t = threadIdx.x;
    const int base = b * SCAN_CHUNK;
    int s = 0;
    #pragma unroll
    for (int i = 0; i < SCAN_CHUNK / 256; i++) {
        const int idx = base + t + i * 256;
        s += (idx < N_NODES) ? deg[idx] : 0;
    }
    sd[t] = s; __syncthreads();
    for (int off = 128; off > 0; off >>= 1) {
        if (t < off) sd[t] += sd[t + off];
        __syncthreads();
    }
    if (t == 0) bsum[b] = sd[0];
}

__global__ __launch_bounds__(256) void scan_block_kernel(
    const int* __restrict__ bsum, int* __restrict__ boff, int* __restrict__ offs)
{
    __shared__ int sd[256];
    const int t = threadIdx.x;
    const int v = (t < NBLK_SCAN) ? bsum[t] : 0;
    sd[t] = v; __syncthreads();
    for (int off = 1; off < 256; off <<= 1) {
        const int u = (t >= off) ? sd[t - off] : 0;
        __syncthreads();
        sd[t] += u;
        __syncthreads();
    }
    if (t < NBLK_SCAN) boff[t] = sd[t] - v;
    if (t == 0) offs[N_NODES] = N_EDGES;
}

__global__ __launch_bounds__(256) void scan_scatter_kernel(
    const int* __restrict__ deg, const int* __restrict__ boff, int* __restrict__ offs)
{
    __shared__ int sd[256];
    const int b = blockIdx.x, t = threadIdx.x;
    const int base = b * SCAN_CHUNK + t * 4;
    int d0 = 0, d1 = 0, d2 = 0, d3 = 0;
    if (base + 0 < N_NODES) d0 = deg[base + 0];
    if (base + 1 < N_NODES) d1 = deg[base + 1];
    if (base + 2 < N_NODES) d2 = deg[base + 2];
    if (base + 3 < N_NODES) d3 = deg[base + 3];
    const int ts = d0 + d1 + d2 + d3;
    sd[t] = ts; __syncthreads();
    for (int off = 1; off < 256; off <<= 1) {
        const int u = (t >= off) ? sd[t - off] : 0;
        __syncthreads();
        sd[t] += u;
        __syncthreads();
    }
    const int excl = sd[t] - ts + boff[b];
    if (base + 0 < N_NODES) offs[base + 0] = excl;
    if (base + 1 < N_NODES) offs[base + 1] = excl + d0;
    if (base + 2 < N_NODES) offs[base + 2] = excl + d0 + d1;
    if (base + 3 < N_NODES) offs[base + 3] = excl + d0 + d1 + d2;
}

// ===========================================================================
// Graph segment offsets: batch is sorted, so goffs[g] = lower_bound(batch, g).
// ===========================================================================
__global__ __launch_bounds__(256) void graph_offs_kernel(
    const int* __restrict__ batch, int* __restrict__ goffs)
{
    const int g = blockIdx.x * 256 + threadIdx.x;
    if (g > NGRAPH) return;
    if (g == NGRAPH) { goffs[NGRAPH] = N_NODES; return; }
    int lo = 0, hi = N_NODES;
    while (lo < hi) {
        const int mid = (lo + hi) >> 1;
        if (batch[mid] < g) lo = mid + 1; else hi = mid;
    }
    goffs[g] = lo;
}

// ===========================================================================
// Pool: one 256-thread block per graph, no atomics, fully coalesced.
// ===========================================================================
__global__ __launch_bounds__(256) void pool_kernel(
    const float* __restrict__ h, const int* __restrict__ goffs,
    float* __restrict__ pooled, float* __restrict__ cnt)
{
    __shared__ float4 red[4][16];
    const int g = blockIdx.x, t = threadIdx.x;
    const int s = goffs[g], e = goffs[g + 1];
    const int grp = t >> 4;      // node group 0..15
    const int q = t & 15;        // float4 slot within node
    float4 acc = {0.f, 0.f, 0.f, 0.f};
    for (int n = s + grp; n < e; n += 16) {
        const float4 v = *(const float4*)(h + (size_t)n * HID + q * 4);
        acc.x += v.x; acc.y += v.y; acc.z += v.z; acc.w += v.w;
    }
    #pragma unroll
    for (int off = 16; off <= 32; off <<= 1) {
        acc.x += __shfl_xor(acc.x, off, 64);
        acc.y += __shfl_xor(acc.y, off, 64);
        acc.z += __shfl_xor(acc.z, off, 64);
        acc.w += __shfl_xor(acc.w, off, 64);
    }
    const int wv = t >> 6, lane = t & 63;
    if (lane < 16) red[wv][lane] = acc;
    __syncthreads();
    if (t < 16) {
        float4 a = red[0][t];
        const float4 b = red[1][t], c = red[2][t], d = red[3][t];
        a.x += b.x + c.x + d.x;
        a.y += b.y + c.y + d.y;
        a.z += b.z + c.z + d.z;
        a.w += b.w + c.w + d.w;
        *(float4*)(pooled + (size_t)g * HID + t * 4) = a;
    }
    if (t == 0) cnt[g] = (float)(e - s);
}

// ===========================================================================
// Embed: h0 = relu(bn(x @ W + b)) via split-bf16 MFMA.
// ===========================================================================
__global__ __launch_bounds__(256) void embed_kernel(
    const float* __restrict__ x, const unsigned short* __restrict__ wpe,
    const float* __restrict__ bias,
    const float* __restrict__ bn_g, const float* __restrict__ bn_b,
    const float* __restrict__ bn_m, const float* __restrict__ bn_v,
    float* __restrict__ h)
{
    __shared__ __align__(16) short Abuf[4 * 4 * 2 * 64 * 8];   // 32 KB
    __shared__ float Ztmp[TILE_N * ZS];                        // 17408 B
    __shared__ float BNs[128];
    const int t = threadIdx.x, lane = t & 63, w = t >> 6;
    const int base = blockIdx.x * TILE_N;

    if (t < 64) {
        const float s = bn_g[t] * rsqrtf(bn_v[t] + BN_EPS);
        BNs[t] = s;
        BNs[64 + t] = bias[t] * s + bn_b[t] - bn_m[t] * s;
    }
    // stage + hi/lo convert x tile into A-frag order
    #pragma unroll
    for (int i = 0; i < 8; i++) {
        const int idx = t + i * 256;                 // 0..2047
        const int n = idx >> 5, k4 = idx & 31;
        const float4 v = *(const float4*)(x + (size_t)(base + n) * IN_DIM + k4 * 4);
        uint2 hi, lo; cvt4(v, hi, lo);
        const int s = k4 >> 3, lc = (n & 15) + 16 * ((k4 >> 1) & 3);
        const int half = k4 & 1, wm = n >> 4;
        *(uint2*)&Abuf[(((wm * 4 + s) * 2 + 0) * 64 + lc) * 8 + half * 4] = hi;
        *(uint2*)&Abuf[(((wm * 4 + s) * 2 + 1) * 64 + lc) * 8 + half * 4] = lo;
    }
    __syncthreads();

    const bf16x8* A = (const bf16x8*)Abuf;
    const bf16x8* B = (const bf16x8*)wpe;
    bf16x8 ah[4], al[4];
    #pragma unroll
    for (int s = 0; s < 4; s++) {
        ah[s] = A[((w * 4 + s) * 2 + 0) * 64 + lane];
        al[s] = A[((w * 4 + s) * 2 + 1) * 64 + lane];
    }
    const int q = lane >> 4, c = lane & 15;
    #pragma unroll
    for (int ct = 0; ct < 4; ct++) {
        f32x4 acc = {0.f, 0.f, 0.f, 0.f};
        #pragma unroll
        for (int s = 0; s < 4; s++) {
            const bf16x8 bh = B[(ct << 9) + (s << 7) + lane];
            const bf16x8 bl = B[(ct << 9) + (s << 7) + 64 + lane];
            acc = MFMA16(ah[s], bh, acc);
            acc = MFMA16(ah[s], bl, acc);
            acc = MFMA16(al[s], bh, acc);
        }
        const int n = ct * 16 + c;
        const float sc = BNs[n], sh = BNs[64 + n];
        #pragma unroll
        for (int r = 0; r < 4; r++)
            Ztmp[(w * 16 + q * 4 + r) * ZS + n] = fmaxf(acc[r] * sc + sh, 0.f);
    }
    __syncthreads();
    #pragma unroll
    for (int i = 0; i < 4; i++) {
        const int idx = t + i * 256, n = idx >> 4, k4 = idx & 15;
        *(float4*)(h + (size_t)(base + n) * HID + k4 * 4) =
            *(const float4*)(&Ztmp[n * ZS + k4 * 4]);
    }
}

// ===========================================================================
// Fused GIN layer (unchanged)
// ===========================================================================
__global__ __launch_bounds__(256) void agg_mlp_kernel(
    const float* __restrict__ hin, float* __restrict__ hout,
    const int* __restrict__ offs, const int* __restrict__ csr,
    const unsigned short* __restrict__ wp1, const unsigned short* __restrict__ wp2,
    const float* __restrict__ b1, const float* __restrict__ g1,
    const float* __restrict__ bb1, const float* __restrict__ m1, const float* __restrict__ v1,
    const float* __restrict__ b2, const float* __restrict__ g2,
    const float* __restrict__ bb2, const float* __restrict__ m2, const float* __restrict__ v2)
{
    __shared__ __align__(16) short Abuf[4 * 2 * 2 * 64 * 8];   // 16 KB
    __shared__ float Ztmp[TILE_N * ZS];                        // 17408 B
    __shared__ int   OF[TILE_N + 1];
    __shared__ int   EIDX[ECAP];                               // 4 KB
    __shared__ float BNs[256];
    const int t = threadIdx.x, lane = t & 63, w = t >> 6;
    const int sub = lane >> 4, cq = lane & 15;
    const int base = blockIdx.x * TILE_N;

    if (t < 64) {
        const float sa = g1[t] * rsqrtf(v1[t] + BN_EPS);
        BNs[t] = sa; BNs[64 + t] = b1[t] * sa + bb1[t] - m1[t] * sa;
        const float sb = g2[t] * rsqrtf(v2[t] + BN_EPS);
        BNs[128 + t] = sb; BNs[192 + t] = b2[t] * sb + bb2[t] - m2[t] * sb;
    }
    if (t <= TILE_N) OF[t] = offs[base + t];
    const int segStart = offs[base];
    const int segEnd   = offs[base + TILE_N];
    for (int i = t; i < segEnd - segStart; i += 256)
        if (i < ECAP) EIDX[i] = csr[segStart + i];
    __syncthreads();

    // gather -> A-frag hi/lo writes
    const float* __restrict__ hc = hin + cq * 4;
    #pragma unroll
    for (int p = 0; p < 4; p++) {
        const int mloc = p * 4 + sub, nl = w * 16 + mloc;
        const int e0 = OF[nl], e1 = OF[nl + 1];
        float4 acc = *(const float4*)(hin + (size_t)(base + nl) * HID + cq * 4);
        if (e0 < e1) {
            const int e1m = e1 - 1;
            for (int e = e0; e < e1; e += 4) {
                const int ea = e;
                const int eb = (e + 1 < e1) ? e + 1 : e1m;
                const int ec = (e + 2 < e1) ? e + 2 : e1m;
                const int ed = (e + 3 < e1) ? e + 3 : e1m;
                const int la = ea - segStart, lb = eb - segStart;
                const int lc2 = ec - segStart, ld = ed - segStart;
                const int s0 = (la < ECAP) ? EIDX[la] : csr[ea];
                const int s1 = (lb < ECAP) ? EIDX[lb] : csr[eb];
                const int s2 = (lc2 < ECAP) ? EIDX[lc2] : csr[ec];
                const int s3 = (ld < ECAP) ? EIDX[ld] : csr[ed];
                const float4 v0 = *(const float4*)(hc + (size_t)s0 * HID);
                const float4 v1_ = *(const float4*)(hc + (size_t)s1 * HID);
                const float4 v2_ = *(const float4*)(hc + (size_t)s2 * HID);
                const float4 v3_ = *(const float4*)(hc + (size_t)s3 * HID);
                const float mk1 = (e + 1 < e1) ? 1.f : 0.f;
                const float mk2 = (e + 2 < e1) ? 1.f : 0.f;
                const float mk3 = (e + 3 < e1) ? 1.f : 0.f;
                acc.x += v0.x + mk1 * v1_.x + mk2 * v2_.x + mk3 * v3_.x;
                acc.y += v0.y + mk1 * v1_.y + mk2 * v2_.y + mk3 * v3_.y;
                acc.z += v0.z + mk1 * v1_.z + mk2 * v2_.z + mk3 * v3_.z;
                acc.w += v0.w + mk1 * v1_.w + mk2 * v2_.w + mk3 * v3_.w;
            }
        }
        uint2 hi, lo; cvt4(acc, hi, lo);
        const int s = cq >> 3, lc = mloc + 16 * ((cq >> 1) & 3), half = cq & 1;
        *(uint2*)&Abuf[(((w * 2 + s) * 2 + 0) * 64 + lc) * 8 + half * 4] = hi;
        *(uint2*)&Abuf[(((w * 2 + s) * 2 + 1) * 64 + lc) * 8 + half * 4] = lo;
    }
    __syncthreads();

    const bf16x8* A = (const bf16x8*)Abuf;
    const int q = lane >> 4, c = lane & 15;

    // GEMM1
    {
        const bf16x8 a0h = A[((w * 2 + 0) * 2 + 0) * 64 + lane];
        const bf16x8 a0l = A[((w * 2 + 0) * 2 + 1) * 64 + lane];
        const bf16x8 a1h = A[((w * 2 + 1) * 2 + 0) * 64 + lane];
        const bf16x8 a1l = A[((w * 2 + 1) * 2 + 1) * 64 + lane];
        const bf16x8* B = (const bf16x8*)wp1;
        #pragma unroll
        for (int ct = 0; ct < 4; ct++) {
            const bf16x8 b0h = B[(ct << 8) + lane];
            const bf16x8 b0l = B[(ct << 8) + 64 + lane];
            const bf16x8 b1h_ = B[(ct << 8) + 128 + lane];
            const bf16x8 b1l_ = B[(ct << 8) + 192 + lane];
            f32x4 acc = {0.f, 0.f, 0.f, 0.f};
            acc = MFMA16(a0h, b0h, acc);
            acc = MFMA16(a0h, b0l, acc);
            acc = MFMA16(a0l, b0h, acc);
            acc = MFMA16(a1h, b1h_, acc);
            acc = MFMA16(a1h, b1l_, acc);
            acc = MFMA16(a1l, b1h_, acc);
            const int n = ct * 16 + c;
            const float sc = BNs[n], sh = BNs[64 + n];
            #pragma unroll
            for (int r = 0; r < 4; r++)
                Ztmp[(w * 16 + q * 4 + r) * ZS + n] = fmaxf(acc[r] * sc + sh, 0.f);
        }
    }
    __syncthreads();    // Ztmp complete; Abuf free

    // re-split t1 into A-frags
    {
        const int m = t >> 2;
        #pragma unroll
        for (int d = 0; d < 4; d++) {
            const int k4 = (t & 3) * 4 + d;
            const float4 v = *(const float4*)(&Ztmp[m * ZS + k4 * 4]);
            uint2 hi, lo; cvt4(v, hi, lo);
            const int s = k4 >> 3, lc = (m & 15) + 16 * ((k4 >> 1) & 3);
            const int half = k4 & 1, wm = m >> 4;
            *(uint2*)&Abuf[(((wm * 2 + s) * 2 + 0) * 64 + lc) * 8 + half * 4] = hi;
            *(uint2*)&Abuf[(((wm * 2 + s) * 2 + 1) * 64 + lc) * 8 + half * 4] = lo;
        }
    }
    __syncthreads();

    // GEMM2
    {
        const bf16x8 a0h = A[((w * 2 + 0) * 2 + 0) * 64 + lane];
        const bf16x8 a0l = A[((w * 2 + 0) * 2 + 1) * 64 + lane];
        const bf16x8 a1h = A[((w * 2 + 1) * 2 + 0) * 64 + lane];
        const bf16x8 a1l = A[((w * 2 + 1) * 2 + 1) * 64 + lane];
        const bf16x8* B = (const bf16x8*)wp2;
        #pragma unroll
        for (int ct = 0; ct < 4; ct++) {
            const bf16x8 b0h = B[(ct << 8) + lane];
            const bf16x8 b0l = B[(ct << 8) + 64 + lane];
            const bf16x8 b1h_ = B[(ct << 8) + 128 + lane];
            const bf16x8 b1l_ = B[(ct << 8) + 192 + lane];
            f32x4 acc = {0.f, 0.f, 0.f, 0.f};
            acc = MFMA16(a0h, b0h, acc);
            acc = MFMA16(a0h, b0l, acc);
            acc = MFMA16(a0l, b0h, acc);
            acc = MFMA16(a1h, b1h_, acc);
            acc = MFMA16(a1h, b1l_, acc);
            acc = MFMA16(a1l, b1h_, acc);
            const int n = ct * 16 + c;
            const float sc = BNs[128 + n], sh = BNs[192 + n];
            #pragma unroll
            for (int r = 0; r < 4; r++)
                Ztmp[(w * 16 + q * 4 + r) * ZS + n] = fmaxf(acc[r] * sc + sh, 0.f);
        }
    }
    __syncthreads();

    #pragma unroll
    for (int i = 0; i < 4; i++) {
        const int idx = t + i * 256, n = idx >> 4, k4 = idx & 15;
        *(float4*)(hout + (size_t)(base + n) * HID + k4 * 4) =
            *(const float4*)(&Ztmp[n * ZS + k4 * 4]);
    }
}

// ===========================================================================
// Classifier (unchanged)
// ===========================================================================
__global__ __launch_bounds__(64) void cls_kernel(
    const float* __restrict__ pooled, const float* __restrict__ cnt,
    const float* __restrict__ w1, const float* __restrict__ b1,
    const float* __restrict__ w2, const float* __restrict__ b2,
    float* __restrict__ out)
{
    const int g = blockIdx.x;
    const int lane = threadIdx.x;
    const float c = cnt[g];
    const float p = pooled[(size_t)g * HID + lane] / fmaxf(c, 1.f);
    float acc = (lane < 32) ? b1[lane] : 0.f;
    #pragma unroll
    for (int k = 0; k < 64; k++) {
        const float pk = __shfl(p, k, 64);
        if (lane < 32) acc += pk * w1[k * 32 + lane];
    }
    const float hmid = fmaxf(acc, 0.f);
    float acc2 = (lane < NCLS) ? b2[lane] : 0.f;
    #pragma unroll
    for (int k = 0; k < 32; k++) {
        const float hk = __shfl(hmid, k, 64);
        if (lane < NCLS) acc2 += hk * w2[k * NCLS + lane];
    }
    if (lane < NCLS) out[(size_t)g * NCLS + lane] = acc2;
}

// ===========================================================================
extern "C" void kernel_launch(void* const* d_in, const int* in_sizes, int n_in,
                              void* d_out, int out_size, void* d_ws, size_t ws_size,
                              hipStream_t stream) {
    const float* x     = (const float*)d_in[0];
    const int*   ei    = (const int*)d_in[1];
    const int*   batch = (const int*)d_in[2];
    const float* emb_w = (const float*)d_in[3];
    const float* emb_b = (const float*)d_in[4];
    const float* ibn_g = (const float*)d_in[5];
    const float* ibn_b = (const float*)d_in[6];
    const float* ibn_m = (const float*)d_in[7];
    const float* ibn_v = (const float*)d_in[8];
    const float* fc1_w = (const float*)d_in[9];
    const float* fc1_b = (const float*)d_in[10];
    const float* mbn_g = (const float*)d_in[11];
    const float* mbn_b = (const float*)d_in[12];
    const float* mbn_m = (const float*)d_in[13];
    const float* mbn_v = (const float*)d_in[14];
    const float* fc2_w = (const float*)d_in[15];
    const float* fc2_b = (const float*)d_in[16];
    const float* obn_g = (const float*)d_in[17];
    const float* obn_b = (const float*)d_in[18];
    const float* obn_m = (const float*)d_in[19];
    const float* obn_v = (const float*)d_in[20];
    const float* cls1w = (const float*)d_in[21];
    const float* cls1b = (const float*)d_in[22];
    const float* cls2w = (const float*)d_in[23];
    const float* cls2b = (const float*)d_in[24];

    float* h0     = (float*)d_ws;
    float* h1     = h0 + (size_t)N_NODES * HID;
    float* pooled = h1 + (size_t)N_NODES * HID;
    float* cnt    = pooled + NGRAPH * HID;
    int*   deg    = (int*)(cnt + NGRAPH);
    int*   offs   = deg + N_NODES;
    int*   bsum   = offs + (N_NODES + 1);
    int*   boff   = bsum + NBLK_SCAN;
    int*   csr    = boff + NBLK_SCAN;
    unsigned short* wpe = (unsigned short*)(csr + N_EDGES);   // 16384
    unsigned short* wpf = wpe + 16384;                        // 49152
    int*   goffs  = (int*)(wpf + 49152);                      // NGRAPH+1
    int*   gcnt   = goffs + (NGRAPH + 1);                     // NBKT
    // ebin reuses h0 space: CSR build completes (stream-ordered) before
    // embed_kernel writes h0. 128*12288*8 B = 12.6 MB << 51.2 MB.
    uint2* ebin   = (uint2*)h0;

    const int* src = ei;
    const int* dst = ei + N_EDGES;

    // weight prep (B-fragment packing, hi/lo planes)
    prep_emb_kernel<<<64, 256, 0, stream>>>(emb_w, wpe);
    prep_fc_kernel<<<192, 256, 0, stream>>>(fc1_w, fc2_w, wpf);

    // graph segment offsets (batch is sorted)
    graph_offs_kernel<<<(NGRAPH + 256) / 256, 256, 0, stream>>>(batch, goffs);

    // binned CSR build
    hipMemsetAsync(gcnt, 0, NBKT * sizeof(int), stream);
    bin_kernel<<<NB_BIN, 256, 0, stream>>>(src, dst, gcnt, ebin);
    bindeg_kernel<<<NBKT, 512, 0, stream>>>(gcnt, ebin, deg);
    scan_sum_kernel<<<NBLK_SCAN, 256, 0, stream>>>(deg, bsum);
    scan_block_kernel<<<1, 256, 0, stream>>>(bsum, boff, offs);
    scan_scatter_kernel<<<NBLK_SCAN, 256, 0, stream>>>(deg, boff, offs);
    binscatter_kernel<<<NBKT, 512, 0, stream>>>(gcnt, ebin, offs, csr);

    // network
    const int gemm_blocks = N_NODES / TILE_N;   // 3125
    embed_kernel<<<gemm_blocks, 256, 0, stream>>>(x, wpe, emb_b,
                                                  ibn_g, ibn_b, ibn_m, ibn_v, h0);

    const float* hin = h0;
    float* hout = h1;
    for (int i = 0; i < 3; i++) {
        agg_mlp_kernel<<<gemm_blocks, 256, 0, stream>>>(
            hin, hout, offs, csr,
            wpf + (size_t)(i * 2 + 0) * 8192, wpf + (size_t)(i * 2 + 1) * 8192,
            fc1_b + i * HID, mbn_g + i * HID, mbn_b + i * HID, mbn_m + i * HID, mbn_v + i * HID,
            fc2_b + i * HID, obn_g + i * HID, obn_b + i * HID, obn_m + i * HID, obn_v + i * HID);
        const float* tmp = hin; hin = hout; hout = (float*)tmp;
    }

    // pool: one block per graph, no atomics
    pool_kernel<<<NGRAPH, 256, 0, stream>>>(h1, goffs, pooled, cnt);

    cls_kernel<<<NGRAPH, 64, 0, stream>>>(pooled, cnt, cls1w, cls1b, cls2w, cls2b,
                                          (float*)d_out);
}

// Round 3
// 497.938 us; speedup vs baseline: 1.3978x; 1.0581x over previous
//
#include <hip/hip_runtime.h>
#include <hip/hip_bf16.h>

#define N_NODES 200000
#define N_EDGES 1200000
#define IN_DIM  128
#define HID     64
#define NGRAPH  1024
#define NCLS    6
#define BN_EPS  1e-5f

#define TILE_N   64
#define ZS       68          // Ztmp row stride (floats); 272B = 17 banks shift, 2-way max
#define ECAP     1024

#define SCAN_CHUNK 1024
#define NBLK_SCAN ((N_NODES + SCAN_CHUNK - 1) / SCAN_CHUNK)   // 196

// ---- binned CSR build ----
#define NBKT   128           // dst-range buckets
#define BRANGE 1568          // nodes per bucket (128*1568 = 200704 >= N)
#define BCAP   12288         // per-bucket edge capacity (mean 9408, sigma ~97)
#define EPB    4096          // edges per bin_kernel block
#define NB_BIN ((N_EDGES + EPB - 1) / EPB)   // 293

// 16B-slot XOR swizzle for A-frag LDS: spreads the j=(k4>>1)&3 sub-tiles
// across banks (write side was 4-way conflicted); reads stay a permutation
// of a contiguous 1KB wave-region -> 2-way (free).
#define SWZ(s) ((s) ^ (((s) >> 4) & 3))

typedef short bf16x8 __attribute__((ext_vector_type(8)));
typedef float f32x4  __attribute__((ext_vector_type(4)));
#define MFMA16(a,b,c) __builtin_amdgcn_mfma_f32_16x16x32_bf16((a),(b),(c),0,0,0)

__device__ __forceinline__ unsigned short f2bf(float f) {
    union { __hip_bfloat16 h; unsigned short u; } v; v.h = __float2bfloat16(f); return v.u;
}
__device__ __forceinline__ float bfbits2f(unsigned short u) {
    union { unsigned int i; float f; } v; v.i = ((unsigned int)u) << 16; return v.f;
}
// float4 -> (hi bf16x4, lo bf16x4) packed as uint2 each
__device__ __forceinline__ void cvt4(const float4& x, uint2& hi, uint2& lo) {
    const unsigned short h0 = f2bf(x.x), h1 = f2bf(x.y), h2 = f2bf(x.z), h3 = f2bf(x.w);
    hi.x = (unsigned)h0 | ((unsigned)h1 << 16);
    hi.y = (unsigned)h2 | ((unsigned)h3 << 16);
    const unsigned short l0 = f2bf(x.x - bfbits2f(h0)), l1 = f2bf(x.y - bfbits2f(h1));
    const unsigned short l2 = f2bf(x.z - bfbits2f(h2)), l3 = f2bf(x.w - bfbits2f(h3));
    lo.x = (unsigned)l0 | ((unsigned)l1 << 16);
    lo.y = (unsigned)l2 | ((unsigned)l3 << 16);
}

// ===========================================================================
// Weight prep: pack W into MFMA B-fragment order (bf16 hi/lo planes).
// ===========================================================================
__global__ __launch_bounds__(256) void prep_emb_kernel(
    const float* __restrict__ w, unsigned short* __restrict__ wpe)   // [128][64] -> 16384
{
    const int idx = blockIdx.x * 256 + threadIdx.x;      // [ct2][s2][p1][l6][j3]
    if (idx >= 16384) return;
    const int j = idx & 7, l = (idx >> 3) & 63;
    const int plane = (idx >> 9) & 1, s = (idx >> 10) & 3, ct = (idx >> 12) & 3;
    const int n = ct * 16 + (l & 15);
    const int k = s * 32 + (l >> 4) * 8 + j;
    const float f = w[k * 64 + n];
    const unsigned short hb = f2bf(f);
    wpe[idx] = plane ? f2bf(f - bfbits2f(hb)) : hb;
}

__global__ __launch_bounds__(256) void prep_fc_kernel(
    const float* __restrict__ fc1, const float* __restrict__ fc2,
    unsigned short* __restrict__ wpf)                    // 3*2*8192 = 49152
{
    const int idx = blockIdx.x * 256 + threadIdx.x;      // [layer][g][ct2][s1][p1][l6][j3]
    if (idx >= 49152) return;
    const int j = idx & 7, l = (idx >> 3) & 63;
    const int plane = (idx >> 9) & 1, s = (idx >> 10) & 1, ct = (idx >> 11) & 3;
    const int g = (idx >> 13) & 1, layer = idx >> 14;
    const int n = ct * 16 + (l & 15);
    const int k = s * 32 + (l >> 4) * 8 + j;
    const float* W = g ? fc2 : fc1;
    const float f = W[(layer * 64 + k) * 64 + n];
    const unsigned short hb = f2bf(f);
    wpf[idx] = plane ? f2bf(f - bfbits2f(hb)) : hb;
}

// ===========================================================================
// Binned CSR build.
// ===========================================================================
__global__ __launch_bounds__(256) void bin_kernel(
    const int* __restrict__ src, const int* __restrict__ dst,
    int* __restrict__ gcnt, uint2* __restrict__ ebin)
{
    __shared__ int hist[NBKT];
    __shared__ int basis[NBKT];
    const int t = threadIdx.x;
    const int base = blockIdx.x * EPB;
    if (t < NBKT) hist[t] = 0;
    __syncthreads();
    int sv[16], dv[16];
    #pragma unroll
    for (int i = 0; i < 16; i++) {
        const int e = base + t + i * 256;
        if (e < N_EDGES) {
            sv[i] = src[e]; dv[i] = dst[e];
            atomicAdd(&hist[dv[i] / BRANGE], 1);
        } else { sv[i] = -1; dv[i] = -1; }
    }
    __syncthreads();
    if (t < NBKT) { basis[t] = atomicAdd(&gcnt[t], hist[t]); hist[t] = 0; }
    __syncthreads();
    #pragma unroll
    for (int i = 0; i < 16; i++) {
        if (dv[i] >= 0) {
            const int bb = dv[i] / BRANGE;
            const int pos = basis[bb] + atomicAdd(&hist[bb], 1);
            ebin[(size_t)bb * BCAP + pos] = make_uint2((unsigned)sv[i], (unsigned)dv[i]);
        }
    }
}

// bindeg: per-bucket LDS histogram -> dense deg write.
__global__ __launch_bounds__(512) void bindeg_kernel(
    const int* __restrict__ gcnt, const uint2* __restrict__ ebin,
    int* __restrict__ deg)
{
    __shared__ int hist[BRANGE];
    const int b = blockIdx.x, t = threadIdx.x;
    for (int i = t; i < BRANGE; i += 512) hist[i] = 0;
    __syncthreads();
    const int cnt = gcnt[b];
    const int r0 = b * BRANGE;
    const uint2* __restrict__ eb = ebin + (size_t)b * BCAP;
    for (int i = t; i < cnt; i += 512)
        atomicAdd(&hist[(int)eb[i].y - r0], 1);
    __syncthreads();
    for (int i = t; i < BRANGE; i += 512)
        if (r0 + i < N_NODES) deg[r0 + i] = hist[i];
}

// binscatter: one block owns one bucket's contiguous csr region; cursors in LDS.
__global__ __launch_bounds__(512) void binscatter_kernel(
    const int* __restrict__ gcnt, const uint2* __restrict__ ebin,
    const int* __restrict__ offs, int* __restrict__ csr_src)
{
    __shared__ int cur[BRANGE];
    const int b = blockIdx.x, t = threadIdx.x;
    const int r0 = b * BRANGE;
    const int lim = (r0 + BRANGE <= N_NODES) ? BRANGE : (N_NODES - r0);
    for (int i = t; i < lim; i += 512) cur[i] = offs[r0 + i];
    __syncthreads();
    const int cnt = gcnt[b];
    const uint2* __restrict__ eb = ebin + (size_t)b * BCAP;
    for (int i = t; i < cnt; i += 512) {
        const uint2 e = eb[i];
        const int pos = atomicAdd(&cur[(int)e.y - r0], 1);
        csr_src[pos] = (int)e.x;
    }
}

// ===========================================================================
// Prefix scan over deg (unchanged)
// ===========================================================================
__global__ __launch_bounds__(256) void scan_sum_kernel(
    const int* __restrict__ deg, int* __restrict__ bsum)
{
    __shared__ int sd[256];
    const int b = blockIdx.x, t = threadIdx.x;
    const int base = b * SCAN_CHUNK;
    int s = 0;
    #pragma unroll
    for (int i = 0; i < SCAN_CHUNK / 256; i++) {
        const int idx = base + t + i * 256;
        s += (idx < N_NODES) ? deg[idx] : 0;
    }
    sd[t] = s; __syncthreads();
    for (int off = 128; off > 0; off >>= 1) {
        if (t < off) sd[t] += sd[t + off];
        __syncthreads();
    }
    if (t == 0) bsum[b] = sd[0];
}

__global__ __launch_bounds__(256) void scan_block_kernel(
    const int* __restrict__ bsum, int* __restrict__ boff, int* __restrict__ offs)
{
    __shared__ int sd[256];
    const int t = threadIdx.x;
    const int v = (t < NBLK_SCAN) ? bsum[t] : 0;
    sd[t] = v; __syncthreads();
    for (int off = 1; off < 256; off <<= 1) {
        const int u = (t >= off) ? sd[t - off] : 0;
        __syncthreads();
        sd[t] += u;
        __syncthreads();
    }
    if (t < NBLK_SCAN) boff[t] = sd[t] - v;
    if (t == 0) offs[N_NODES] = N_EDGES;
}

__global__ __launch_bounds__(256) void scan_scatter_kernel(
    const int* __restrict__ deg, const int* __restrict__ boff, int* __restrict__ offs)
{
    __shared__ int sd[256];
    const int b = blockIdx.x, t = threadIdx.x;
    const int base = b * SCAN_CHUNK + t * 4;
    int d0 = 0, d1 = 0, d2 = 0, d3 = 0;
    if (base + 0 < N_NODES) d0 = deg[base + 0];
    if (base + 1 < N_NODES) d1 = deg[base + 1];
    if (base + 2 < N_NODES) d2 = deg[base + 2];
    if (base + 3 < N_NODES) d3 = deg[base + 3];
    const int ts = d0 + d1 + d2 + d3;
    sd[t] = ts; __syncthreads();
    for (int off = 1; off < 256; off <<= 1) {
        const int u = (t >= off) ? sd[t - off] : 0;
        __syncthreads();
        sd[t] += u;
        __syncthreads();
    }
    const int excl = sd[t] - ts + boff[b];
    if (base + 0 < N_NODES) offs[base + 0] = excl;
    if (base + 1 < N_NODES) offs[base + 1] = excl + d0;
    if (base + 2 < N_NODES) offs[base + 2] = excl + d0 + d1;
    if (base + 3 < N_NODES) offs[base + 3] = excl + d0 + d1 + d2;
}

// ===========================================================================
// Graph segment offsets: batch is sorted, so goffs[g] = lower_bound(batch, g).
// ===========================================================================
__global__ __launch_bounds__(256) void graph_offs_kernel(
    const int* __restrict__ batch, int* __restrict__ goffs)
{
    const int g = blockIdx.x * 256 + threadIdx.x;
    if (g > NGRAPH) return;
    if (g == NGRAPH) { goffs[NGRAPH] = N_NODES; return; }
    int lo = 0, hi = N_NODES;
    while (lo < hi) {
        const int mid = (lo + hi) >> 1;
        if (batch[mid] < g) lo = mid + 1; else hi = mid;
    }
    goffs[g] = lo;
}

// ===========================================================================
// Pool: one 256-thread block per graph, no atomics, fully coalesced.
// ===========================================================================
__global__ __launch_bounds__(256) void pool_kernel(
    const float* __restrict__ h, const int* __restrict__ goffs,
    float* __restrict__ pooled, float* __restrict__ cnt)
{
    __shared__ float4 red[4][16];
    const int g = blockIdx.x, t = threadIdx.x;
    const int s = goffs[g], e = goffs[g + 1];
    const int grp = t >> 4;      // node group 0..15
    const int q = t & 15;        // float4 slot within node
    float4 acc = {0.f, 0.f, 0.f, 0.f};
    for (int n = s + grp; n < e; n += 16) {
        const float4 v = *(const float4*)(h + (size_t)n * HID + q * 4);
        acc.x += v.x; acc.y += v.y; acc.z += v.z; acc.w += v.w;
    }
    #pragma unroll
    for (int off = 16; off <= 32; off <<= 1) {
        acc.x += __shfl_xor(acc.x, off, 64);
        acc.y += __shfl_xor(acc.y, off, 64);
        acc.z += __shfl_xor(acc.z, off, 64);
        acc.w += __shfl_xor(acc.w, off, 64);
    }
    const int wv = t >> 6, lane = t & 63;
    if (lane < 16) red[wv][lane] = acc;
    __syncthreads();
    if (t < 16) {
        float4 a = red[0][t];
        const float4 b = red[1][t], c = red[2][t], d = red[3][t];
        a.x += b.x + c.x + d.x;
        a.y += b.y + c.y + d.y;
        a.z += b.z + c.z + d.z;
        a.w += b.w + c.w + d.w;
        *(float4*)(pooled + (size_t)g * HID + t * 4) = a;
    }
    if (t == 0) cnt[g] = (float)(e - s);
}

// ===========================================================================
// Embed: h0 = relu(bn(x @ W + b)) via split-bf16 MFMA.
// Abuf/Ztmp now UNIONED (frag loads -> barrier -> Ztmp writes): LDS 50.7->33.3KB.
// ===========================================================================
__global__ __launch_bounds__(256) void embed_kernel(
    const float* __restrict__ x, const unsigned short* __restrict__ wpe,
    const float* __restrict__ bias,
    const float* __restrict__ bn_g, const float* __restrict__ bn_b,
    const float* __restrict__ bn_m, const float* __restrict__ bn_v,
    float* __restrict__ h)
{
    __shared__ __align__(16) float Ush[8192];                  // 32 KB union
    __shared__ float BNs[128];
    short* Abuf = (short*)Ush;
    float* Ztmp = Ush;
    const int t = threadIdx.x, lane = t & 63, w = t >> 6;
    const int base = blockIdx.x * TILE_N;

    if (t < 64) {
        const float s = bn_g[t] * rsqrtf(bn_v[t] + BN_EPS);
        BNs[t] = s;
        BNs[64 + t] = bias[t] * s + bn_b[t] - bn_m[t] * s;
    }
    // stage + hi/lo convert x tile into A-frag order (swizzled slots)
    #pragma unroll
    for (int i = 0; i < 8; i++) {
        const int idx = t + i * 256;                 // 0..2047
        const int n = idx >> 5, k4 = idx & 31;
        const float4 v = *(const float4*)(x + (size_t)(base + n) * IN_DIM + k4 * 4);
        uint2 hi, lo; cvt4(v, hi, lo);
        const int s = k4 >> 3, lc = (n & 15) + 16 * ((k4 >> 1) & 3);
        const int half = k4 & 1, wm = n >> 4;
        const int sl0 = ((wm * 4 + s) * 2 + 0) * 64 + lc;
        const int sl1 = ((wm * 4 + s) * 2 + 1) * 64 + lc;
        *(uint2*)&Abuf[SWZ(sl0) * 8 + half * 4] = hi;
        *(uint2*)&Abuf[SWZ(sl1) * 8 + half * 4] = lo;
    }
    __syncthreads();

    const bf16x8* A = (const bf16x8*)Abuf;
    const bf16x8* B = (const bf16x8*)wpe;
    bf16x8 ah[4], al[4];
    #pragma unroll
    for (int s = 0; s < 4; s++) {
        ah[s] = A[SWZ(((w * 4 + s) * 2 + 0) * 64 + lane)];
        al[s] = A[SWZ(((w * 4 + s) * 2 + 1) * 64 + lane)];
    }
    __syncthreads();    // all frag reads done; Ztmp may overwrite Abuf
    const int q = lane >> 4, c = lane & 15;
    #pragma unroll
    for (int ct = 0; ct < 4; ct++) {
        f32x4 acc = {0.f, 0.f, 0.f, 0.f};
        #pragma unroll
        for (int s = 0; s < 4; s++) {
            const bf16x8 bh = B[(ct << 9) + (s << 7) + lane];
            const bf16x8 bl = B[(ct << 9) + (s << 7) + 64 + lane];
            acc = MFMA16(ah[s], bh, acc);
            acc = MFMA16(ah[s], bl, acc);
            acc = MFMA16(al[s], bh, acc);
        }
        const int n = ct * 16 + c;
        const float sc = BNs[n], sh = BNs[64 + n];
        #pragma unroll
        for (int r = 0; r < 4; r++)
            Ztmp[(w * 16 + q * 4 + r) * ZS + n] = fmaxf(acc[r] * sc + sh, 0.f);
    }
    __syncthreads();
    #pragma unroll
    for (int i = 0; i < 4; i++) {
        const int idx = t + i * 256, n = idx >> 4, k4 = idx & 15;
        *(float4*)(h + (size_t)(base + n) * HID + k4 * 4) =
            *(const float4*)(&Ztmp[n * ZS + k4 * 4]);
    }
}

// ===========================================================================
// Fused GIN layer. Abuf/Ztmp UNIONED: LDS 39.4 -> 22.8 KB -> 7 blocks/CU.
// Extra barriers guard the alias (frag loads to regs before Ztmp writes;
// register-staged re-split).
// ===========================================================================
__global__ __launch_bounds__(256, 7) void agg_mlp_kernel(
    const float* __restrict__ hin, float* __restrict__ hout,
    const int* __restrict__ offs, const int* __restrict__ csr,
    const unsigned short* __restrict__ wp1, const unsigned short* __restrict__ wp2,
    const float* __restrict__ b1, const float* __restrict__ g1,
    const float* __restrict__ bb1, const float* __restrict__ m1, const float* __restrict__ v1,
    const float* __restrict__ b2, const float* __restrict__ g2,
    const float* __restrict__ bb2, const float* __restrict__ m2, const float* __restrict__ v2)
{
    __shared__ __align__(16) float Ush[TILE_N * ZS];           // 17408 B union
    __shared__ int   OF[TILE_N + 1];
    __shared__ int   EIDX[ECAP];                               // 4 KB
    __shared__ float BNs[256];
    short* Abuf = (short*)Ush;
    float* Ztmp = Ush;
    const int t = threadIdx.x, lane = t & 63, w = t >> 6;
    const int sub = lane >> 4, cq = lane & 15;
    const int base = blockIdx.x * TILE_N;

    if (t < 64) {
        const float sa = g1[t] * rsqrtf(v1[t] + BN_EPS);
        BNs[t] = sa; BNs[64 + t] = b1[t] * sa + bb1[t] - m1[t] * sa;
        const float sb = g2[t] * rsqrtf(v2[t] + BN_EPS);
        BNs[128 + t] = sb; BNs[192 + t] = b2[t] * sb + bb2[t] - m2[t] * sb;
    }
    if (t <= TILE_N) OF[t] = offs[base + t];
    const int segStart = offs[base];
    const int segEnd   = offs[base + TILE_N];
    for (int i = t; i < segEnd - segStart; i += 256)
        if (i < ECAP) EIDX[i] = csr[segStart + i];
    __syncthreads();

    // gather -> A-frag hi/lo writes (swizzled slots)
    const float* __restrict__ hc = hin + cq * 4;
    #pragma unroll
    for (int p = 0; p < 4; p++) {
        const int mloc = p * 4 + sub, nl = w * 16 + mloc;
        const int e0 = OF[nl], e1 = OF[nl + 1];
        float4 acc = *(const float4*)(hin + (size_t)(base + nl) * HID + cq * 4);
        if (e0 < e1) {
            const int e1m = e1 - 1;
            for (int e = e0; e < e1; e += 4) {
                const int ea = e;
                const int eb = (e + 1 < e1) ? e + 1 : e1m;
                const int ec = (e + 2 < e1) ? e + 2 : e1m;
                const int ed = (e + 3 < e1) ? e + 3 : e1m;
                const int la = ea - segStart, lb = eb - segStart;
                const int lc2 = ec - segStart, ld = ed - segStart;
                const int s0 = (la < ECAP) ? EIDX[la] : csr[ea];
                const int s1 = (lb < ECAP) ? EIDX[lb] : csr[eb];
                const int s2 = (lc2 < ECAP) ? EIDX[lc2] : csr[ec];
                const int s3 = (ld < ECAP) ? EIDX[ld] : csr[ed];
                const float4 v0 = *(const float4*)(hc + (size_t)s0 * HID);
                const float4 v1_ = *(const float4*)(hc + (size_t)s1 * HID);
                const float4 v2_ = *(const float4*)(hc + (size_t)s2 * HID);
                const float4 v3_ = *(const float4*)(hc + (size_t)s3 * HID);
                const float mk1 = (e + 1 < e1) ? 1.f : 0.f;
                const float mk2 = (e + 2 < e1) ? 1.f : 0.f;
                const float mk3 = (e + 3 < e1) ? 1.f : 0.f;
                acc.x += v0.x + mk1 * v1_.x + mk2 * v2_.x + mk3 * v3_.x;
                acc.y += v0.y + mk1 * v1_.y + mk2 * v2_.y + mk3 * v3_.y;
                acc.z += v0.z + mk1 * v1_.z + mk2 * v2_.z + mk3 * v3_.z;
                acc.w += v0.w + mk1 * v1_.w + mk2 * v2_.w + mk3 * v3_.w;
            }
        }
        uint2 hi, lo; cvt4(acc, hi, lo);
        const int s = cq >> 3, lc = mloc + 16 * ((cq >> 1) & 3), half = cq & 1;
        const int sl0 = ((w * 2 + s) * 2 + 0) * 64 + lc;
        const int sl1 = ((w * 2 + s) * 2 + 1) * 64 + lc;
        *(uint2*)&Abuf[SWZ(sl0) * 8 + half * 4] = hi;
        *(uint2*)&Abuf[SWZ(sl1) * 8 + half * 4] = lo;
    }
    __syncthreads();

    const bf16x8* A = (const bf16x8*)Abuf;
    const int q = lane >> 4, c = lane & 15;

    // GEMM1
    {
        const bf16x8 a0h = A[SWZ(((w * 2 + 0) * 2 + 0) * 64 + lane)];
        const bf16x8 a0l = A[SWZ(((w * 2 + 0) * 2 + 1) * 64 + lane)];
        const bf16x8 a1h = A[SWZ(((w * 2 + 1) * 2 + 0) * 64 + lane)];
        const bf16x8 a1l = A[SWZ(((w * 2 + 1) * 2 + 1) * 64 + lane)];
        __syncthreads();    // frag reads done; Ztmp writes may alias Abuf
        const bf16x8* B = (const bf16x8*)wp1;
        #pragma unroll
        for (int ct = 0; ct < 4; ct++) {
            const bf16x8 b0h = B[(ct << 8) + lane];
            const bf16x8 b0l = B[(ct << 8) + 64 + lane];
            const bf16x8 b1h_ = B[(ct << 8) + 128 + lane];
            const bf16x8 b1l_ = B[(ct << 8) + 192 + lane];
            f32x4 acc = {0.f, 0.f, 0.f, 0.f};
            acc = MFMA16(a0h, b0h, acc);
            acc = MFMA16(a0h, b0l, acc);
            acc = MFMA16(a0l, b0h, acc);
            acc = MFMA16(a1h, b1h_, acc);
            acc = MFMA16(a1h, b1l_, acc);
            acc = MFMA16(a1l, b1h_, acc);
            const int n = ct * 16 + c;
            const float sc = BNs[n], sh = BNs[64 + n];
            #pragma unroll
            for (int r = 0; r < 4; r++)
                Ztmp[(w * 16 + q * 4 + r) * ZS + n] = fmaxf(acc[r] * sc + sh, 0.f);
        }
    }
    __syncthreads();    // Ztmp complete

    // re-split t1 into A-frags (register-staged: read all, barrier, write)
    {
        const int m = t >> 2;
        float4 vv[4];
        #pragma unroll
        for (int d = 0; d < 4; d++) {
            const int k4 = (t & 3) * 4 + d;
            vv[d] = *(const float4*)(&Ztmp[m * ZS + k4 * 4]);
        }
        __syncthreads();    // Ztmp reads done; A-frag writes may alias
        #pragma unroll
        for (int d = 0; d < 4; d++) {
            const int k4 = (t & 3) * 4 + d;
            uint2 hi, lo; cvt4(vv[d], hi, lo);
            const int s = k4 >> 3, lc = (m & 15) + 16 * ((k4 >> 1) & 3);
            const int half = k4 & 1, wm = m >> 4;
            const int sl0 = ((wm * 2 + s) * 2 + 0) * 64 + lc;
            const int sl1 = ((wm * 2 + s) * 2 + 1) * 64 + lc;
            *(uint2*)&Abuf[SWZ(sl0) * 8 + half * 4] = hi;
            *(uint2*)&Abuf[SWZ(sl1) * 8 + half * 4] = lo;
        }
    }
    __syncthreads();

    // GEMM2
    {
        const bf16x8 a0h = A[SWZ(((w * 2 + 0) * 2 + 0) * 64 + lane)];
        const bf16x8 a0l = A[SWZ(((w * 2 + 0) * 2 + 1) * 64 + lane)];
        const bf16x8 a1h = A[SWZ(((w * 2 + 1) * 2 + 0) * 64 + lane)];
        const bf16x8 a1l = A[SWZ(((w * 2 + 1) * 2 + 1) * 64 + lane)];
        __syncthreads();    // frag reads done; Ztmp writes may alias Abuf
        const bf16x8* B = (const bf16x8*)wp2;
        #pragma unroll
        for (int ct = 0; ct < 4; ct++) {
            const bf16x8 b0h = B[(ct << 8) + lane];
            const bf16x8 b0l = B[(ct << 8) + 64 + lane];
            const bf16x8 b1h_ = B[(ct << 8) + 128 + lane];
            const bf16x8 b1l_ = B[(ct << 8) + 192 + lane];
            f32x4 acc = {0.f, 0.f, 0.f, 0.f};
            acc = MFMA16(a0h, b0h, acc);
            acc = MFMA16(a0h, b0l, acc);
            acc = MFMA16(a0l, b0h, acc);
            acc = MFMA16(a1h, b1h_, acc);
            acc = MFMA16(a1h, b1l_, acc);
            acc = MFMA16(a1l, b1h_, acc);
            const int n = ct * 16 + c;
            const float sc = BNs[128 + n], sh = BNs[192 + n];
            #pragma unroll
            for (int r = 0; r < 4; r++)
                Ztmp[(w * 16 + q * 4 + r) * ZS + n] = fmaxf(acc[r] * sc + sh, 0.f);
        }
    }
    __syncthreads();

    #pragma unroll
    for (int i = 0; i < 4; i++) {
        const int idx = t + i * 256, n = idx >> 4, k4 = idx & 15;
        *(float4*)(hout + (size_t)(base + n) * HID + k4 * 4) =
            *(const float4*)(&Ztmp[n * ZS + k4 * 4]);
    }
}

// ===========================================================================
// Classifier (unchanged)
// ===========================================================================
__global__ __launch_bounds__(64) void cls_kernel(
    const float* __restrict__ pooled, const float* __restrict__ cnt,
    const float* __restrict__ w1, const float* __restrict__ b1,
    const float* __restrict__ w2, const float* __restrict__ b2,
    float* __restrict__ out)
{
    const int g = blockIdx.x;
    const int lane = threadIdx.x;
    const float c = cnt[g];
    const float p = pooled[(size_t)g * HID + lane] / fmaxf(c, 1.f);
    float acc = (lane < 32) ? b1[lane] : 0.f;
    #pragma unroll
    for (int k = 0; k < 64; k++) {
        const float pk = __shfl(p, k, 64);
        if (lane < 32) acc += pk * w1[k * 32 + lane];
    }
    const float hmid = fmaxf(acc, 0.f);
    float acc2 = (lane < NCLS) ? b2[lane] : 0.f;
    #pragma unroll
    for (int k = 0; k < 32; k++) {
        const float hk = __shfl(hmid, k, 64);
        if (lane < NCLS) acc2 += hk * w2[k * NCLS + lane];
    }
    if (lane < NCLS) out[(size_t)g * NCLS + lane] = acc2;
}

// ===========================================================================
extern "C" void kernel_launch(void* const* d_in, const int* in_sizes, int n_in,
                              void* d_out, int out_size, void* d_ws, size_t ws_size,
                              hipStream_t stream) {
    const float* x     = (const float*)d_in[0];
    const int*   ei    = (const int*)d_in[1];
    const int*   batch = (const int*)d_in[2];
    const float* emb_w = (const float*)d_in[3];
    const float* emb_b = (const float*)d_in[4];
    const float* ibn_g = (const float*)d_in[5];
    const float* ibn_b = (const float*)d_in[6];
    const float* ibn_m = (const float*)d_in[7];
    const float* ibn_v = (const float*)d_in[8];
    const float* fc1_w = (const float*)d_in[9];
    const float* fc1_b = (const float*)d_in[10];
    const float* mbn_g = (const float*)d_in[11];
    const float* mbn_b = (const float*)d_in[12];
    const float* mbn_m = (const float*)d_in[13];
    const float* mbn_v = (const float*)d_in[14];
    const float* fc2_w = (const float*)d_in[15];
    const float* fc2_b = (const float*)d_in[16];
    const float* obn_g = (const float*)d_in[17];
    const float* obn_b = (const float*)d_in[18];
    const float* obn_m = (const float*)d_in[19];
    const float* obn_v = (const float*)d_in[20];
    const float* cls1w = (const float*)d_in[21];
    const float* cls1b = (const float*)d_in[22];
    const float* cls2w = (const float*)d_in[23];
    const float* cls2b = (const float*)d_in[24];

    float* h0     = (float*)d_ws;
    float* h1     = h0 + (size_t)N_NODES * HID;
    float* pooled = h1 + (size_t)N_NODES * HID;
    float* cnt    = pooled + NGRAPH * HID;
    int*   deg    = (int*)(cnt + NGRAPH);
    int*   offs   = deg + N_NODES;
    int*   bsum   = offs + (N_NODES + 1);
    int*   boff   = bsum + NBLK_SCAN;
    int*   csr    = boff + NBLK_SCAN;
    unsigned short* wpe = (unsigned short*)(csr + N_EDGES);   // 16384
    unsigned short* wpf = wpe + 16384;                        // 49152
    int*   goffs  = (int*)(wpf + 49152);                      // NGRAPH+1
    int*   gcnt   = goffs + (NGRAPH + 1);                     // NBKT
    // ebin reuses h0 space: CSR build completes (stream-ordered) before
    // embed_kernel writes h0. 128*12288*8 B = 12.6 MB << 51.2 MB.
    uint2* ebin   = (uint2*)h0;

    const int* src = ei;
    const int* dst = ei + N_EDGES;

    // weight prep (B-fragment packing, hi/lo planes)
    prep_emb_kernel<<<64, 256, 0, stream>>>(emb_w, wpe);
    prep_fc_kernel<<<192, 256, 0, stream>>>(fc1_w, fc2_w, wpf);

    // graph segment offsets (batch is sorted)
    graph_offs_kernel<<<(NGRAPH + 256) / 256, 256, 0, stream>>>(batch, goffs);

    // binned CSR build
    hipMemsetAsync(gcnt, 0, NBKT * sizeof(int), stream);
    bin_kernel<<<NB_BIN, 256, 0, stream>>>(src, dst, gcnt, ebin);
    bindeg_kernel<<<NBKT, 512, 0, stream>>>(gcnt, ebin, deg);
    scan_sum_kernel<<<NBLK_SCAN, 256, 0, stream>>>(deg, bsum);
    scan_block_kernel<<<1, 256, 0, stream>>>(bsum, boff, offs);
    scan_scatter_kernel<<<NBLK_SCAN, 256, 0, stream>>>(deg, boff, offs);
    binscatter_kernel<<<NBKT, 512, 0, stream>>>(gcnt, ebin, offs, csr);

    // network
    const int gemm_blocks = N_NODES / TILE_N;   // 3125
    embed_kernel<<<gemm_blocks, 256, 0, stream>>>(x, wpe, emb_b,
                                                  ibn_g, ibn_b, ibn_m, ibn_v, h0);

    const float* hin = h0;
    float* hout = h1;
    for (int i = 0; i < 3; i++) {
        agg_mlp_kernel<<<gemm_blocks, 256, 0, stream>>>(
            hin, hout, offs, csr,
            wpf + (size_t)(i * 2 + 0) * 8192, wpf + (size_t)(i * 2 + 1) * 8192,
            fc1_b + i * HID, mbn_g + i * HID, mbn_b + i * HID, mbn_m + i * HID, mbn_v + i * HID,
            fc2_b + i * HID, obn_g + i * HID, obn_b + i * HID, obn_m + i * HID, obn_v + i * HID);
        const float* tmp = hin; hin = hout; hout = (float*)tmp;
    }

    // pool: one block per graph, no atomics
    pool_kernel<<<NGRAPH, 256, 0, stream>>>(h1, goffs, pooled, cnt);

    cls_kernel<<<NGRAPH, 64, 0, stream>>>(pooled, cnt, cls1w, cls1b, cls2w, cls2b,
                                          (float*)d_out);
}

// Round 4
// 489.440 us; speedup vs baseline: 1.4220x; 1.0174x over previous
//
#include <hip/hip_runtime.h>
#include <hip/hip_bf16.h>

#define N_NODES 200000
#define N_EDGES 1200000
#define IN_DIM  128
#define HID     64
#define NGRAPH  1024
#define NCLS    6
#define BN_EPS  1e-5f

#define TILE_N   64
#define ZS       68          // Ztmp row stride (floats); 272B = 17 banks shift, 2-way max
#define ECAP     1024

#define SCAN_CHUNK 1024
#define NBLK_SCAN ((N_NODES + SCAN_CHUNK - 1) / SCAN_CHUNK)   // 196

// ---- binned CSR build ----
#define NBKT   128           // dst-range buckets
#define BRANGE 1568          // nodes per bucket (128*1568 = 200704 >= N)
#define BCAP   12288         // per-bucket edge capacity (mean 9408, sigma ~97)
#define EPB    4096          // edges per bin_kernel block
#define NB_BIN ((N_EDGES + EPB - 1) / EPB)   // 293

// 16B-slot XOR swizzle for A-frag LDS
#define SWZ(s) ((s) ^ (((s) >> 4) & 3))

typedef short bf16x8 __attribute__((ext_vector_type(8)));
typedef float f32x4  __attribute__((ext_vector_type(4)));
#define MFMA16(a,b,c) __builtin_amdgcn_mfma_f32_16x16x32_bf16((a),(b),(c),0,0,0)

__device__ __forceinline__ unsigned short f2bf(float f) {
    union { __hip_bfloat16 h; unsigned short u; } v; v.h = __float2bfloat16(f); return v.u;
}
__device__ __forceinline__ float bfbits2f(unsigned short u) {
    union { unsigned int i; float f; } v; v.i = ((unsigned int)u) << 16; return v.f;
}
// float4 -> (hi bf16x4, lo bf16x4) packed as uint2 each
__device__ __forceinline__ void cvt4(const float4& x, uint2& hi, uint2& lo) {
    const unsigned short h0 = f2bf(x.x), h1 = f2bf(x.y), h2 = f2bf(x.z), h3 = f2bf(x.w);
    hi.x = (unsigned)h0 | ((unsigned)h1 << 16);
    hi.y = (unsigned)h2 | ((unsigned)h3 << 16);
    const unsigned short l0 = f2bf(x.x - bfbits2f(h0)), l1 = f2bf(x.y - bfbits2f(h1));
    const unsigned short l2 = f2bf(x.z - bfbits2f(h2)), l3 = f2bf(x.w - bfbits2f(h3));
    lo.x = (unsigned)l0 | ((unsigned)l1 << 16);
    lo.y = (unsigned)l2 | ((unsigned)l3 << 16);
}

// ===========================================================================
// Weight prep: pack W into MFMA B-fragment order (bf16 hi/lo planes).
// ===========================================================================
__global__ __launch_bounds__(256) void prep_emb_kernel(
    const float* __restrict__ w, unsigned short* __restrict__ wpe)   // [128][64] -> 16384
{
    const int idx = blockIdx.x * 256 + threadIdx.x;      // [ct2][s2][p1][l6][j3]
    if (idx >= 16384) return;
    const int j = idx & 7, l = (idx >> 3) & 63;
    const int plane = (idx >> 9) & 1, s = (idx >> 10) & 3, ct = (idx >> 12) & 3;
    const int n = ct * 16 + (l & 15);
    const int k = s * 32 + (l >> 4) * 8 + j;
    const float f = w[k * 64 + n];
    const unsigned short hb = f2bf(f);
    wpe[idx] = plane ? f2bf(f - bfbits2f(hb)) : hb;
}

__global__ __launch_bounds__(256) void prep_fc_kernel(
    const float* __restrict__ fc1, const float* __restrict__ fc2,
    unsigned short* __restrict__ wpf)                    // 3*2*8192 = 49152
{
    const int idx = blockIdx.x * 256 + threadIdx.x;      // [layer][g][ct2][s1][p1][l6][j3]
    if (idx >= 49152) return;
    const int j = idx & 7, l = (idx >> 3) & 63;
    const int plane = (idx >> 9) & 1, s = (idx >> 10) & 1, ct = (idx >> 11) & 3;
    const int g = (idx >> 13) & 1, layer = idx >> 14;
    const int n = ct * 16 + (l & 15);
    const int k = s * 32 + (l >> 4) * 8 + j;
    const float* W = g ? fc2 : fc1;
    const float f = W[(layer * 64 + k) * 64 + n];
    const unsigned short hb = f2bf(f);
    wpf[idx] = plane ? f2bf(f - bfbits2f(hb)) : hb;
}

// ===========================================================================
// Binned CSR build.
// ===========================================================================
__global__ __launch_bounds__(256) void bin_kernel(
    const int* __restrict__ src, const int* __restrict__ dst,
    int* __restrict__ gcnt, uint2* __restrict__ ebin)
{
    __shared__ int hist[NBKT];
    __shared__ int basis[NBKT];
    const int t = threadIdx.x;
    const int base = blockIdx.x * EPB;
    if (t < NBKT) hist[t] = 0;
    __syncthreads();
    int sv[16], dv[16];
    #pragma unroll
    for (int i = 0; i < 16; i++) {
        const int e = base + t + i * 256;
        if (e < N_EDGES) {
            sv[i] = src[e]; dv[i] = dst[e];
            atomicAdd(&hist[dv[i] / BRANGE], 1);
        } else { sv[i] = -1; dv[i] = -1; }
    }
    __syncthreads();
    if (t < NBKT) { basis[t] = atomicAdd(&gcnt[t], hist[t]); hist[t] = 0; }
    __syncthreads();
    #pragma unroll
    for (int i = 0; i < 16; i++) {
        if (dv[i] >= 0) {
            const int bb = dv[i] / BRANGE;
            const int pos = basis[bb] + atomicAdd(&hist[bb], 1);
            ebin[(size_t)bb * BCAP + pos] = make_uint2((unsigned)sv[i], (unsigned)dv[i]);
        }
    }
}

// bindeg: per-bucket LDS histogram -> dense deg write.
__global__ __launch_bounds__(512) void bindeg_kernel(
    const int* __restrict__ gcnt, const uint2* __restrict__ ebin,
    int* __restrict__ deg)
{
    __shared__ int hist[BRANGE];
    const int b = blockIdx.x, t = threadIdx.x;
    for (int i = t; i < BRANGE; i += 512) hist[i] = 0;
    __syncthreads();
    const int cnt = gcnt[b];
    const int r0 = b * BRANGE;
    const uint2* __restrict__ eb = ebin + (size_t)b * BCAP;
    for (int i = t; i < cnt; i += 512)
        atomicAdd(&hist[(int)eb[i].y - r0], 1);
    __syncthreads();
    for (int i = t; i < BRANGE; i += 512)
        if (r0 + i < N_NODES) deg[r0 + i] = hist[i];
}

// binscatter: one block owns one bucket's contiguous csr region; cursors in LDS.
__global__ __launch_bounds__(512) void binscatter_kernel(
    const int* __restrict__ gcnt, const uint2* __restrict__ ebin,
    const int* __restrict__ offs, int* __restrict__ csr_src)
{
    __shared__ int cur[BRANGE];
    const int b = blockIdx.x, t = threadIdx.x;
    const int r0 = b * BRANGE;
    const int lim = (r0 + BRANGE <= N_NODES) ? BRANGE : (N_NODES - r0);
    for (int i = t; i < lim; i += 512) cur[i] = offs[r0 + i];
    __syncthreads();
    const int cnt = gcnt[b];
    const uint2* __restrict__ eb = ebin + (size_t)b * BCAP;
    for (int i = t; i < cnt; i += 512) {
        const uint2 e = eb[i];
        const int pos = atomicAdd(&cur[(int)e.y - r0], 1);
        csr_src[pos] = (int)e.x;
    }
}

// ===========================================================================
// Prefix scan over deg (unchanged)
// ===========================================================================
__global__ __launch_bounds__(256) void scan_sum_kernel(
    const int* __restrict__ deg, int* __restrict__ bsum)
{
    __shared__ int sd[256];
    const int b = blockIdx.x, t = threadIdx.x;
    const int base = b * SCAN_CHUNK;
    int s = 0;
    #pragma unroll
    for (int i = 0; i < SCAN_CHUNK / 256; i++) {
        const int idx = base + t + i * 256;
        s += (idx < N_NODES) ? deg[idx] : 0;
    }
    sd[t] = s; __syncthreads();
    for (int off = 128; off > 0; off >>= 1) {
        if (t < off) sd[t] += sd[t + off];
        __syncthreads();
    }
    if (t == 0) bsum[b] = sd[0];
}

__global__ __launch_bounds__(256) void scan_block_kernel(
    const int* __restrict__ bsum, int* __restrict__ boff, int* __restrict__ offs)
{
    __shared__ int sd[256];
    const int t = threadIdx.x;
    const int v = (t < NBLK_SCAN) ? bsum[t] : 0;
    sd[t] = v; __syncthreads();
    for (int off = 1; off < 256; off <<= 1) {
        const int u = (t >= off) ? sd[t - off] : 0;
        __syncthreads();
        sd[t] += u;
        __syncthreads();
    }
    if (t < NBLK_SCAN) boff[t] = sd[t] - v;
    if (t == 0) offs[N_NODES] = N_EDGES;
}

__global__ __launch_bounds__(256) void scan_scatter_kernel(
    const int* __restrict__ deg, const int* __restrict__ boff, int* __restrict__ offs)
{
    __shared__ int sd[256];
    const int b = blockIdx.x, t = threadIdx.x;
    const int base = b * SCAN_CHUNK + t * 4;
    int d0 = 0, d1 = 0, d2 = 0, d3 = 0;
    if (base + 0 < N_NODES) d0 = deg[base + 0];
    if (base + 1 < N_NODES) d1 = deg[base + 1];
    if (base + 2 < N_NODES) d2 = deg[base + 2];
    if (base + 3 < N_NODES) d3 = deg[base + 3];
    const int ts = d0 + d1 + d2 + d3;
    sd[t] = ts; __syncthreads();
    for (int off = 1; off < 256; off <<= 1) {
        const int u = (t >= off) ? sd[t - off] : 0;
        __syncthreads();
        sd[t] += u;
        __syncthreads();
    }
    const int excl = sd[t] - ts + boff[b];
    if (base + 0 < N_NODES) offs[base + 0] = excl;
    if (base + 1 < N_NODES) offs[base + 1] = excl + d0;
    if (base + 2 < N_NODES) offs[base + 2] = excl + d0 + d1;
    if (base + 3 < N_NODES) offs[base + 3] = excl + d0 + d1 + d2;
}

// ===========================================================================
// Graph segment offsets: batch is sorted, so goffs[g] = lower_bound(batch, g).
// ===========================================================================
__global__ __launch_bounds__(256) void graph_offs_kernel(
    const int* __restrict__ batch, int* __restrict__ goffs)
{
    const int g = blockIdx.x * 256 + threadIdx.x;
    if (g > NGRAPH) return;
    if (g == NGRAPH) { goffs[NGRAPH] = N_NODES; return; }
    int lo = 0, hi = N_NODES;
    while (lo < hi) {
        const int mid = (lo + hi) >> 1;
        if (batch[mid] < g) lo = mid + 1; else hi = mid;
    }
    goffs[g] = lo;
}

// ===========================================================================
// Pool: one 256-thread block per graph, no atomics, fully coalesced.
// ===========================================================================
__global__ __launch_bounds__(256) void pool_kernel(
    const float* __restrict__ h, const int* __restrict__ goffs,
    float* __restrict__ pooled, float* __restrict__ cnt)
{
    __shared__ float4 red[4][16];
    const int g = blockIdx.x, t = threadIdx.x;
    const int s = goffs[g], e = goffs[g + 1];
    const int grp = t >> 4;      // node group 0..15
    const int q = t & 15;        // float4 slot within node
    float4 acc = {0.f, 0.f, 0.f, 0.f};
    for (int n = s + grp; n < e; n += 16) {
        const float4 v = *(const float4*)(h + (size_t)n * HID + q * 4);
        acc.x += v.x; acc.y += v.y; acc.z += v.z; acc.w += v.w;
    }
    #pragma unroll
    for (int off = 16; off <= 32; off <<= 1) {
        acc.x += __shfl_xor(acc.x, off, 64);
        acc.y += __shfl_xor(acc.y, off, 64);
        acc.z += __shfl_xor(acc.z, off, 64);
        acc.w += __shfl_xor(acc.w, off, 64);
    }
    const int wv = t >> 6, lane = t & 63;
    if (lane < 16) red[wv][lane] = acc;
    __syncthreads();
    if (t < 16) {
        float4 a = red[0][t];
        const float4 b = red[1][t], c = red[2][t], d = red[3][t];
        a.x += b.x + c.x + d.x;
        a.y += b.y + c.y + d.y;
        a.z += b.z + c.z + d.z;
        a.w += b.w + c.w + d.w;
        *(float4*)(pooled + (size_t)g * HID + t * 4) = a;
    }
    if (t == 0) cnt[g] = (float)(e - s);
}

// ===========================================================================
// Embed: h0 = relu(bn(x @ W + b)) via split-bf16 MFMA. (unchanged)
// ===========================================================================
__global__ __launch_bounds__(256) void embed_kernel(
    const float* __restrict__ x, const unsigned short* __restrict__ wpe,
    const float* __restrict__ bias,
    const float* __restrict__ bn_g, const float* __restrict__ bn_b,
    const float* __restrict__ bn_m, const float* __restrict__ bn_v,
    float* __restrict__ h)
{
    __shared__ __align__(16) float Ush[8192];                  // 32 KB union
    __shared__ float BNs[128];
    short* Abuf = (short*)Ush;
    float* Ztmp = Ush;
    const int t = threadIdx.x, lane = t & 63, w = t >> 6;
    const int base = blockIdx.x * TILE_N;

    if (t < 64) {
        const float s = bn_g[t] * rsqrtf(bn_v[t] + BN_EPS);
        BNs[t] = s;
        BNs[64 + t] = bias[t] * s + bn_b[t] - bn_m[t] * s;
    }
    // stage + hi/lo convert x tile into A-frag order (swizzled slots)
    #pragma unroll
    for (int i = 0; i < 8; i++) {
        const int idx = t + i * 256;                 // 0..2047
        const int n = idx >> 5, k4 = idx & 31;
        const float4 v = *(const float4*)(x + (size_t)(base + n) * IN_DIM + k4 * 4);
        uint2 hi, lo; cvt4(v, hi, lo);
        const int s = k4 >> 3, lc = (n & 15) + 16 * ((k4 >> 1) & 3);
        const int half = k4 & 1, wm = n >> 4;
        const int sl0 = ((wm * 4 + s) * 2 + 0) * 64 + lc;
        const int sl1 = ((wm * 4 + s) * 2 + 1) * 64 + lc;
        *(uint2*)&Abuf[SWZ(sl0) * 8 + half * 4] = hi;
        *(uint2*)&Abuf[SWZ(sl1) * 8 + half * 4] = lo;
    }
    __syncthreads();

    const bf16x8* A = (const bf16x8*)Abuf;
    const bf16x8* B = (const bf16x8*)wpe;
    bf16x8 ah[4], al[4];
    #pragma unroll
    for (int s = 0; s < 4; s++) {
        ah[s] = A[SWZ(((w * 4 + s) * 2 + 0) * 64 + lane)];
        al[s] = A[SWZ(((w * 4 + s) * 2 + 1) * 64 + lane)];
    }
    __syncthreads();    // all frag reads done; Ztmp may overwrite Abuf
    const int q = lane >> 4, c = lane & 15;
    #pragma unroll
    for (int ct = 0; ct < 4; ct++) {
        f32x4 acc = {0.f, 0.f, 0.f, 0.f};
        #pragma unroll
        for (int s = 0; s < 4; s++) {
            const bf16x8 bh = B[(ct << 9) + (s << 7) + lane];
            const bf16x8 bl = B[(ct << 9) + (s << 7) + 64 + lane];
            acc = MFMA16(ah[s], bh, acc);
            acc = MFMA16(ah[s], bl, acc);
            acc = MFMA16(al[s], bh, acc);
        }
        const int n = ct * 16 + c;
        const float sc = BNs[n], sh = BNs[64 + n];
        #pragma unroll
        for (int r = 0; r < 4; r++)
            Ztmp[(w * 16 + q * 4 + r) * ZS + n] = fmaxf(acc[r] * sc + sh, 0.f);
    }
    __syncthreads();
    #pragma unroll
    for (int i = 0; i < 4; i++) {
        const int idx = t + i * 256, n = idx >> 4, k4 = idx & 15;
        *(float4*)(h + (size_t)(base + n) * HID + k4 * 4) =
            *(const float4*)(&Ztmp[n * ZS + k4 * 4]);
    }
}

// ===========================================================================
// Fused GIN layer. Gather restructured: 2 concurrent node-chains x 4-deep
// = 8 outstanding float4 gathers per lane (was 4, serial per node).
// ===========================================================================
__global__ __launch_bounds__(256, 6) void agg_mlp_kernel(
    const float* __restrict__ hin, float* __restrict__ hout,
    const int* __restrict__ offs, const int* __restrict__ csr,
    const unsigned short* __restrict__ wp1, const unsigned short* __restrict__ wp2,
    const float* __restrict__ b1, const float* __restrict__ g1,
    const float* __restrict__ bb1, const float* __restrict__ m1, const float* __restrict__ v1,
    const float* __restrict__ b2, const float* __restrict__ g2,
    const float* __restrict__ bb2, const float* __restrict__ m2, const float* __restrict__ v2)
{
    __shared__ __align__(16) float Ush[TILE_N * ZS];           // 17408 B union
    __shared__ int   OF[TILE_N + 1];
    __shared__ int   EIDX[ECAP];                               // 4 KB
    __shared__ float BNs[256];
    short* Abuf = (short*)Ush;
    float* Ztmp = Ush;
    const int t = threadIdx.x, lane = t & 63, w = t >> 6;
    const int sub = lane >> 4, cq = lane & 15;
    const int base = blockIdx.x * TILE_N;

    if (t < 64) {
        const float sa = g1[t] * rsqrtf(v1[t] + BN_EPS);
        BNs[t] = sa; BNs[64 + t] = b1[t] * sa + bb1[t] - m1[t] * sa;
        const float sb = g2[t] * rsqrtf(v2[t] + BN_EPS);
        BNs[128 + t] = sb; BNs[192 + t] = b2[t] * sb + bb2[t] - m2[t] * sb;
    }
    if (t <= TILE_N) OF[t] = offs[base + t];
    const int segStart = offs[base];
    const int segEnd   = offs[base + TILE_N];
    for (int i = t; i < segEnd - segStart; i += 256)
        if (i < ECAP) EIDX[i] = csr[segStart + i];
    __syncthreads();

    // gather -> A-frag hi/lo writes (swizzled slots)
    // two chains (A,B) advance together: 8 independent loads per wait
    const float* __restrict__ hc = hin + cq * 4;
    #pragma unroll
    for (int pp = 0; pp < 2; pp++) {
        const int mlA = (pp * 2 + 0) * 4 + sub;
        const int mlB = (pp * 2 + 1) * 4 + sub;
        const int nlA = w * 16 + mlA, nlB = w * 16 + mlB;
        int eA = OF[nlA]; const int eA1 = OF[nlA + 1];
        int eB = OF[nlB]; const int eB1 = OF[nlB + 1];
        // clamp targets stay inside [segStart, segEnd): deg-0-safe
        const int eAm = (eA1 - 1 > segStart) ? eA1 - 1 : segStart;
        const int eBm = (eB1 - 1 > segStart) ? eB1 - 1 : segStart;
        float4 accA = *(const float4*)(hin + (size_t)(base + nlA) * HID + cq * 4);
        float4 accB = *(const float4*)(hin + (size_t)(base + nlB) * HID + cq * 4);
        while (eA < eA1 || eB < eB1) {
            int ia[4], ib[4];
            #pragma unroll
            for (int k = 0; k < 4; k++) {
                const int ea = (eA + k < eAm) ? eA + k : eAm;
                const int eb = (eB + k < eBm) ? eB + k : eBm;
                const int la = ea - segStart, lb = eb - segStart;
                ia[k] = (la < ECAP) ? EIDX[la] : csr[ea];
                ib[k] = (lb < ECAP) ? EIDX[lb] : csr[eb];
            }
            float4 va[4], vb[4];
            #pragma unroll
            for (int k = 0; k < 4; k++) {
                va[k] = *(const float4*)(hc + (size_t)ia[k] * HID);
                vb[k] = *(const float4*)(hc + (size_t)ib[k] * HID);
            }
            #pragma unroll
            for (int k = 0; k < 4; k++) {
                const float ma = (eA + k < eA1) ? 1.f : 0.f;
                const float mb = (eB + k < eB1) ? 1.f : 0.f;
                accA.x += ma * va[k].x; accA.y += ma * va[k].y;
                accA.z += ma * va[k].z; accA.w += ma * va[k].w;
                accB.x += mb * vb[k].x; accB.y += mb * vb[k].y;
                accB.z += mb * vb[k].z; accB.w += mb * vb[k].w;
            }
            eA += 4; eB += 4;
        }
        {
            uint2 hi, lo; cvt4(accA, hi, lo);
            const int s = cq >> 3, lc = mlA + 16 * ((cq >> 1) & 3), half = cq & 1;
            const int sl0 = ((w * 2 + s) * 2 + 0) * 64 + lc;
            const int sl1 = ((w * 2 + s) * 2 + 1) * 64 + lc;
            *(uint2*)&Abuf[SWZ(sl0) * 8 + half * 4] = hi;
            *(uint2*)&Abuf[SWZ(sl1) * 8 + half * 4] = lo;
        }
        {
            uint2 hi, lo; cvt4(accB, hi, lo);
            const int s = cq >> 3, lc = mlB + 16 * ((cq >> 1) & 3), half = cq & 1;
            const int sl0 = ((w * 2 + s) * 2 + 0) * 64 + lc;
            const int sl1 = ((w * 2 + s) * 2 + 1) * 64 + lc;
            *(uint2*)&Abuf[SWZ(sl0) * 8 + half * 4] = hi;
            *(uint2*)&Abuf[SWZ(sl1) * 8 + half * 4] = lo;
        }
    }
    __syncthreads();

    const bf16x8* A = (const bf16x8*)Abuf;
    const int q = lane >> 4, c = lane & 15;

    // GEMM1
    {
        const bf16x8 a0h = A[SWZ(((w * 2 + 0) * 2 + 0) * 64 + lane)];
        const bf16x8 a0l = A[SWZ(((w * 2 + 0) * 2 + 1) * 64 + lane)];
        const bf16x8 a1h = A[SWZ(((w * 2 + 1) * 2 + 0) * 64 + lane)];
        const bf16x8 a1l = A[SWZ(((w * 2 + 1) * 2 + 1) * 64 + lane)];
        __syncthreads();    // frag reads done; Ztmp writes may alias Abuf
        const bf16x8* B = (const bf16x8*)wp1;
        #pragma unroll
        for (int ct = 0; ct < 4; ct++) {
            const bf16x8 b0h = B[(ct << 8) + lane];
            const bf16x8 b0l = B[(ct << 8) + 64 + lane];
            const bf16x8 b1h_ = B[(ct << 8) + 128 + lane];
            const bf16x8 b1l_ = B[(ct << 8) + 192 + lane];
            f32x4 acc = {0.f, 0.f, 0.f, 0.f};
            acc = MFMA16(a0h, b0h, acc);
            acc = MFMA16(a0h, b0l, acc);
            acc = MFMA16(a0l, b0h, acc);
            acc = MFMA16(a1h, b1h_, acc);
            acc = MFMA16(a1h, b1l_, acc);
            acc = MFMA16(a1l, b1h_, acc);
            const int n = ct * 16 + c;
            const float sc = BNs[n], sh = BNs[64 + n];
            #pragma unroll
            for (int r = 0; r < 4; r++)
                Ztmp[(w * 16 + q * 4 + r) * ZS + n] = fmaxf(acc[r] * sc + sh, 0.f);
        }
    }
    __syncthreads();    // Ztmp complete

    // re-split t1 into A-frags (register-staged: read all, barrier, write)
    {
        const int m = t >> 2;
        float4 vv[4];
        #pragma unroll
        for (int d = 0; d < 4; d++) {
            const int k4 = (t & 3) * 4 + d;
            vv[d] = *(const float4*)(&Ztmp[m * ZS + k4 * 4]);
        }
        __syncthreads();    // Ztmp reads done; A-frag writes may alias
        #pragma unroll
        for (int d = 0; d < 4; d++) {
            const int k4 = (t & 3) * 4 + d;
            uint2 hi, lo; cvt4(vv[d], hi, lo);
            const int s = k4 >> 3, lc = (m & 15) + 16 * ((k4 >> 1) & 3);
            const int half = k4 & 1, wm = m >> 4;
            const int sl0 = ((wm * 2 + s) * 2 + 0) * 64 + lc;
            const int sl1 = ((wm * 2 + s) * 2 + 1) * 64 + lc;
            *(uint2*)&Abuf[SWZ(sl0) * 8 + half * 4] = hi;
            *(uint2*)&Abuf[SWZ(sl1) * 8 + half * 4] = lo;
        }
    }
    __syncthreads();

    // GEMM2
    {
        const bf16x8 a0h = A[SWZ(((w * 2 + 0) * 2 + 0) * 64 + lane)];
        const bf16x8 a0l = A[SWZ(((w * 2 + 0) * 2 + 1) * 64 + lane)];
        const bf16x8 a1h = A[SWZ(((w * 2 + 1) * 2 + 0) * 64 + lane)];
        const bf16x8 a1l = A[SWZ(((w * 2 + 1) * 2 + 1) * 64 + lane)];
        __syncthreads();    // frag reads done; Ztmp writes may alias Abuf
        const bf16x8* B = (const bf16x8*)wp2;
        #pragma unroll
        for (int ct = 0; ct < 4; ct++) {
            const bf16x8 b0h = B[(ct << 8) + lane];
            const bf16x8 b0l = B[(ct << 8) + 64 + lane];
            const bf16x8 b1h_ = B[(ct << 8) + 128 + lane];
            const bf16x8 b1l_ = B[(ct << 8) + 192 + lane];
            f32x4 acc = {0.f, 0.f, 0.f, 0.f};
            acc = MFMA16(a0h, b0h, acc);
            acc = MFMA16(a0h, b0l, acc);
            acc = MFMA16(a0l, b0h, acc);
            acc = MFMA16(a1h, b1h_, acc);
            acc = MFMA16(a1h, b1l_, acc);
            acc = MFMA16(a1l, b1h_, acc);
            const int n = ct * 16 + c;
            const float sc = BNs[128 + n], sh = BNs[192 + n];
            #pragma unroll
            for (int r = 0; r < 4; r++)
                Ztmp[(w * 16 + q * 4 + r) * ZS + n] = fmaxf(acc[r] * sc + sh, 0.f);
        }
    }
    __syncthreads();

    #pragma unroll
    for (int i = 0; i < 4; i++) {
        const int idx = t + i * 256, n = idx >> 4, k4 = idx & 15;
        *(float4*)(hout + (size_t)(base + n) * HID + k4 * 4) =
            *(const float4*)(&Ztmp[n * ZS + k4 * 4]);
    }
}

// ===========================================================================
// Classifier (unchanged)
// ===========================================================================
__global__ __launch_bounds__(64) void cls_kernel(
    const float* __restrict__ pooled, const float* __restrict__ cnt,
    const float* __restrict__ w1, const float* __restrict__ b1,
    const float* __restrict__ w2, const float* __restrict__ b2,
    float* __restrict__ out)
{
    const int g = blockIdx.x;
    const int lane = threadIdx.x;
    const float c = cnt[g];
    const float p = pooled[(size_t)g * HID + lane] / fmaxf(c, 1.f);
    float acc = (lane < 32) ? b1[lane] : 0.f;
    #pragma unroll
    for (int k = 0; k < 64; k++) {
        const float pk = __shfl(p, k, 64);
        if (lane < 32) acc += pk * w1[k * 32 + lane];
    }
    const float hmid = fmaxf(acc, 0.f);
    float acc2 = (lane < NCLS) ? b2[lane] : 0.f;
    #pragma unroll
    for (int k = 0; k < 32; k++) {
        const float hk = __shfl(hmid, k, 64);
        if (lane < NCLS) acc2 += hk * w2[k * NCLS + lane];
    }
    if (lane < NCLS) out[(size_t)g * NCLS + lane] = acc2;
}

// ===========================================================================
extern "C" void kernel_launch(void* const* d_in, const int* in_sizes, int n_in,
                              void* d_out, int out_size, void* d_ws, size_t ws_size,
                              hipStream_t stream) {
    const float* x     = (const float*)d_in[0];
    const int*   ei    = (const int*)d_in[1];
    const int*   batch = (const int*)d_in[2];
    const float* emb_w = (const float*)d_in[3];
    const float* emb_b = (const float*)d_in[4];
    const float* ibn_g = (const float*)d_in[5];
    const float* ibn_b = (const float*)d_in[6];
    const float* ibn_m = (const float*)d_in[7];
    const float* ibn_v = (const float*)d_in[8];
    const float* fc1_w = (const float*)d_in[9];
    const float* fc1_b = (const float*)d_in[10];
    const float* mbn_g = (const float*)d_in[11];
    const float* mbn_b = (const float*)d_in[12];
    const float* mbn_m = (const float*)d_in[13];
    const float* mbn_v = (const float*)d_in[14];
    const float* fc2_w = (const float*)d_in[15];
    const float* fc2_b = (const float*)d_in[16];
    const float* obn_g = (const float*)d_in[17];
    const float* obn_b = (const float*)d_in[18];
    const float* obn_m = (const float*)d_in[19];
    const float* obn_v = (const float*)d_in[20];
    const float* cls1w = (const float*)d_in[21];
    const float* cls1b = (const float*)d_in[22];
    const float* cls2w = (const float*)d_in[23];
    const float* cls2b = (const float*)d_in[24];

    float* h0     = (float*)d_ws;
    float* h1     = h0 + (size_t)N_NODES * HID;
    float* pooled = h1 + (size_t)N_NODES * HID;
    float* cnt    = pooled + NGRAPH * HID;
    int*   deg    = (int*)(cnt + NGRAPH);
    int*   offs   = deg + N_NODES;
    int*   bsum   = offs + (N_NODES + 1);
    int*   boff   = bsum + NBLK_SCAN;
    int*   csr    = boff + NBLK_SCAN;
    unsigned short* wpe = (unsigned short*)(csr + N_EDGES);   // 16384
    unsigned short* wpf = wpe + 16384;                        // 49152
    int*   goffs  = (int*)(wpf + 49152);                      // NGRAPH+1
    int*   gcnt   = goffs + (NGRAPH + 1);                     // NBKT
    // ebin reuses h0 space: CSR build completes (stream-ordered) before
    // embed_kernel writes h0. 128*12288*8 B = 12.6 MB << 51.2 MB.
    uint2* ebin   = (uint2*)h0;

    const int* src = ei;
    const int* dst = ei + N_EDGES;

    // weight prep (B-fragment packing, hi/lo planes)
    prep_emb_kernel<<<64, 256, 0, stream>>>(emb_w, wpe);
    prep_fc_kernel<<<192, 256, 0, stream>>>(fc1_w, fc2_w, wpf);

    // graph segment offsets (batch is sorted)
    graph_offs_kernel<<<(NGRAPH + 256) / 256, 256, 0, stream>>>(batch, goffs);

    // binned CSR build
    hipMemsetAsync(gcnt, 0, NBKT * sizeof(int), stream);
    bin_kernel<<<NB_BIN, 256, 0, stream>>>(src, dst, gcnt, ebin);
    bindeg_kernel<<<NBKT, 512, 0, stream>>>(gcnt, ebin, deg);
    scan_sum_kernel<<<NBLK_SCAN, 256, 0, stream>>>(deg, bsum);
    scan_block_kernel<<<1, 256, 0, stream>>>(bsum, boff, offs);
    scan_scatter_kernel<<<NBLK_SCAN, 256, 0, stream>>>(deg, boff, offs);
    binscatter_kernel<<<NBKT, 512, 0, stream>>>(gcnt, ebin, offs, csr);

    // network
    const int gemm_blocks = N_NODES / TILE_N;   // 3125
    embed_kernel<<<gemm_blocks, 256, 0, stream>>>(x, wpe, emb_b,
                                                  ibn_g, ibn_b, ibn_m, ibn_v, h0);

    const float* hin = h0;
    float* hout = h1;
    for (int i = 0; i < 3; i++) {
        agg_mlp_kernel<<<gemm_blocks, 256, 0, stream>>>(
            hin, hout, offs, csr,
            wpf + (size_t)(i * 2 + 0) * 8192, wpf + (size_t)(i * 2 + 1) * 8192,
            fc1_b + i * HID, mbn_g + i * HID, mbn_b + i * HID, mbn_m + i * HID, mbn_v + i * HID,
            fc2_b + i * HID, obn_g + i * HID, obn_b + i * HID, obn_m + i * HID, obn_v + i * HID);
        const float* tmp = hin; hin = hout; hout = (float*)tmp;
    }

    // pool: one block per graph, no atomics
    pool_kernel<<<NGRAPH, 256, 0, stream>>>(h1, goffs, pooled, cnt);

    cls_kernel<<<NGRAPH, 64, 0, stream>>>(pooled, cnt, cls1w, cls1b, cls2w, cls2b,
                                          (float*)d_out);
}